// Round 1
// baseline (4451.390 us; speedup 1.0000x reference)
//
#include <hip/hip_runtime.h>
#include <cstdint>
#include <cstddef>

#define EPSV 1e-5f

// ================= K0: conv 3->32, 32x32, BN+ReLU =================
__global__ __launch_bounds__(256) void conv0_kernel(
    const float* __restrict__ x, const float* __restrict__ w,
    const float* __restrict__ bias, const float* __restrict__ g,
    const float* __restrict__ bt, const float* __restrict__ rm,
    const float* __restrict__ rv, float* __restrict__ out)
{
    const int blk = blockIdx.x;            // 2048 blocks
    const int img = blk >> 2;
    const int p = ((blk & 3) << 8) | (int)threadIdx.x;   // pixel 0..1023
    const int y = p >> 5, xx = p & 31;
    const float* xin = x + (size_t)img * 3 * 1024;
    float xv[3][9];
    #pragma unroll
    for (int ci = 0; ci < 3; ++ci)
      #pragma unroll
      for (int ky = 0; ky < 3; ++ky)
        #pragma unroll
        for (int kx = 0; kx < 3; ++kx) {
            int yy = y + ky - 1, xc = xx + kx - 1;
            bool v = (yy >= 0) && (yy < 32) && (xc >= 0) && (xc < 32);
            xv[ci][ky*3+kx] = v ? xin[ci*1024 + yy*32 + xc] : 0.0f;
        }
    float* ob = out + (size_t)img * 32 * 1024 + p;
    #pragma unroll 4
    for (int co = 0; co < 32; ++co) {
        float s = g[co] / sqrtf(rv[co] + EPSV);
        float c = (bias[co] - rm[co]) * s + bt[co];
        float acc = 0.f;
        #pragma unroll
        for (int ci = 0; ci < 3; ++ci)
          #pragma unroll
          for (int k = 0; k < 9; ++k)
            acc += w[(co*3 + ci)*9 + k] * xv[ci][k];
        float v = acc * s + c;
        ob[co*1024] = v > 0.f ? v : 0.f;
    }
}

// ========== Templated conv+BN+ReLU (+pool) (+avg->feats) ==========
// thread = 2x2 output patch; co-tile = COT; per-ci input plane staged in LDS.
template<int CIN, int COUT, int HW, int COT, bool POOL, bool AVG>
__global__ __launch_bounds__(256, 2) void convT_kernel(
    const float* __restrict__ x, const float* __restrict__ w,
    const float* __restrict__ bias, const float* __restrict__ g,
    const float* __restrict__ bt, const float* __restrict__ rm,
    const float* __restrict__ rv, float* __restrict__ out)
{
    constexpr int PH = HW / 2;
    constexpr int PATCHES = PH * PH;       // threads (patches) per image
    constexpr int IMGS = 256 / PATCHES;    // 1 (HW=32) or 4 (HW=16)
    constexpr int LW = HW + 2;
    constexpr int NZ = COUT / COT;
    __shared__ float plane[IMGS][LW * LW];

    const int imgGroup = blockIdx.x / NZ;
    const int coBase = (blockIdx.x % NZ) * COT;
    const int wave = (int)threadIdx.x >> 6;
    const int img = (IMGS == 1) ? imgGroup : imgGroup * IMGS + wave;
    const int patch = (IMGS == 1) ? (int)threadIdx.x : ((int)threadIdx.x & 63);
    const int py = patch / PH, px = patch % PH;
    const int oy = py * 2, ox = px * 2;

    // zero whole LDS (ring stays zero; interior overwritten each ci)
    for (int t = threadIdx.x; t < IMGS * LW * LW; t += 256)
        (&plane[0][0])[t] = 0.f;

    const float* xin = x + (size_t)img * CIN * HW * HW;
    float* myp = &plane[(IMGS == 1) ? 0 : wave][0];

    float acc[COT][4];
    #pragma unroll
    for (int co = 0; co < COT; ++co)
      #pragma unroll
      for (int q = 0; q < 4; ++q) acc[co][q] = 0.f;

    float pre[4];
    #pragma unroll
    for (int q = 0; q < 4; ++q) pre[q] = xin[patch + q * PATCHES];

    for (int ci = 0; ci < CIN; ++ci) {
        __syncthreads();                    // prior reads done (or zero-fill done)
        #pragma unroll
        for (int q = 0; q < 4; ++q) {
            int pix = patch + q * PATCHES;
            int yy = pix / HW, xc = pix % HW;
            myp[(yy + 1) * LW + (xc + 1)] = pre[q];
        }
        __syncthreads();
        if (ci + 1 < CIN) {                 // register prefetch of next plane
            const float* nx = xin + (size_t)(ci + 1) * HW * HW;
            #pragma unroll
            for (int q = 0; q < 4; ++q) pre[q] = nx[patch + q * PATCHES];
        }
        float xv[4][4];
        #pragma unroll
        for (int dy = 0; dy < 4; ++dy)
          #pragma unroll
          for (int dx = 0; dx < 4; ++dx)
            xv[dy][dx] = myp[(oy + dy) * LW + ox + dx];
        const float* wci = w + ((size_t)coBase * CIN + ci) * 9;
        #pragma unroll
        for (int co = 0; co < COT; ++co) {
            const float* wp = wci + (size_t)co * CIN * 9;   // wave-uniform -> s_load
            float w0=wp[0],w1=wp[1],w2=wp[2],w3=wp[3],w4=wp[4],
                  w5=wp[5],w6=wp[6],w7=wp[7],w8=wp[8];
            #pragma unroll
            for (int pq = 0; pq < 4; ++pq) {
                int ry = pq >> 1, rx = pq & 1;
                float a = acc[co][pq];
                a += w0*xv[ry][rx];   a += w1*xv[ry][rx+1];   a += w2*xv[ry][rx+2];
                a += w3*xv[ry+1][rx]; a += w4*xv[ry+1][rx+1]; a += w5*xv[ry+1][rx+2];
                a += w6*xv[ry+2][rx]; a += w7*xv[ry+2][rx+1]; a += w8*xv[ry+2][rx+2];
                acc[co][pq] = a;
            }
        }
    }

    #pragma unroll 4
    for (int co = 0; co < COT; ++co) {
        const int coG = coBase + co;
        float s = g[coG] / sqrtf(rv[coG] + EPSV);
        float c = (bias[coG] - rm[coG]) * s + bt[coG];
        float v0 = acc[co][0]*s + c; v0 = v0 > 0.f ? v0 : 0.f;
        float v1 = acc[co][1]*s + c; v1 = v1 > 0.f ? v1 : 0.f;
        float v2 = acc[co][2]*s + c; v2 = v2 > 0.f ? v2 : 0.f;
        float v3 = acc[co][3]*s + c; v3 = v3 > 0.f ? v3 : 0.f;
        if constexpr (!POOL) {
            float* ob = out + ((size_t)img * COUT + coG) * HW * HW;
            ob[(oy    )*HW + ox    ] = v0;
            ob[(oy    )*HW + ox + 1] = v1;
            ob[(oy + 1)*HW + ox    ] = v2;
            ob[(oy + 1)*HW + ox + 1] = v3;
        } else {
            float m = fmaxf(fmaxf(v0, v1), fmaxf(v2, v3));
            if constexpr (!AVG) {
                out[((size_t)img * COUT + coG) * PH * PH + py * PH + px] = m;
            } else {
                float sum = m;                        // mean over 8x8 pooled = 64 lanes
                #pragma unroll
                for (int off = 32; off >= 1; off >>= 1)
                    sum += __shfl_xor(sum, off, 64);
                if ((threadIdx.x & 63) == 0)
                    out[(size_t)img * COUT + coG] = sum * (1.0f / 64.0f);
            }
        }
    }
}

// ============== K4: head GEMM + log-softmax + conf ==============
__global__ __launch_bounds__(128) void head_kernel(
    const float* __restrict__ feats, const float* __restrict__ cls_w,
    const float* __restrict__ cls_b, float* __restrict__ logits,
    float* __restrict__ conf)
{
    __shared__ float f[256];
    __shared__ float wt[80 * 65];   // +1 pad breaks 64-stride bank conflict
    __shared__ float lg[80];
    const int b = blockIdx.x, tid = (int)threadIdx.x;
    f[tid] = feats[b * 256 + tid];
    f[tid + 128] = feats[b * 256 + tid + 128];
    float acc = 0.f;
    for (int ch = 0; ch < 4; ++ch) {
        __syncthreads();
        for (int q = tid; q < 80 * 64; q += 128) {
            int r = q >> 6, cc = q & 63;
            wt[r * 65 + cc] = cls_w[r * 256 + ch * 64 + cc];
        }
        __syncthreads();
        if (tid < 80) {
            #pragma unroll 8
            for (int dd = 0; dd < 64; ++dd)
                acc += wt[tid * 65 + dd] * f[ch * 64 + dd];
        }
    }
    if (tid < 80) {
        acc += cls_b[tid];
        logits[b * 80 + tid] = acc;
        lg[tid] = acc;
    }
    __syncthreads();
    if (tid < 80 && (tid % 10) == 0) {
        const int e = tid / 10;
        float m = lg[e * 10];
        for (int cc = 1; cc < 10; ++cc) m = fmaxf(m, lg[e * 10 + cc]);
        float ssum = 0.f;
        for (int cc = 0; cc < 10; ++cc) ssum += expf(lg[e * 10 + cc] - m);
        float lz = m + logf(ssum);
        float cf = 0.f;
        for (int cc = 0; cc < 10; ++cc) {
            float lp = lg[e * 10 + cc] - lz;
            cf += expf(lp) * lp;
        }
        conf[b * 8 + e] = cf;
    }
}

// ======= K5: routing (4x [rescale -> bitonic sort -> greedy scan]) + final =======
__global__ __launch_bounds__(1024) void route_kernel(
    const float* __restrict__ confG,   // [512*8]
    const float* __restrict__ logitsG, // [512*80]
    float* __restrict__ outv)          // [5120 final | 4096 conf | 4096 D]
{
    __shared__ float val[4096];
    __shared__ unsigned short sidx[4096];
    __shared__ unsigned char Dls[512];
    __shared__ int ec[8];
    __shared__ int assignedS;
    const int tid = (int)threadIdx.x;
    if (tid < 512) Dls[tid] = 0;
    if (tid < 8) ec[tid] = 0;
    if (tid == 0) assignedS = 0;
    __syncthreads();

    for (int cycle = 0; cycle < 4; ++cycle) {
        // keys: current = conf * (1 - ec/CAP)   (cycle 0: ec=0 -> conf*1.0 bitwise)
        for (int t = tid; t < 4096; t += 1024) {
            float sc = 1.0f - ((float)ec[t & 7]) / 160.0f;
            val[t] = confG[t] * sc;
            sidx[t] = (unsigned short)t;
        }
        // bitonic sort: descending val, ascending idx on ties == stable argsort(-x)
        for (int k = 2; k <= 4096; k <<= 1)
            for (int j = k >> 1; j > 0; j >>= 1) {
                __syncthreads();
                for (int t = tid; t < 2048; t += 1024) {
                    int i = ((t & ~(j - 1)) << 1) | (t & (j - 1));
                    int p = i | j;
                    float va = val[i], vb = val[p];
                    unsigned short ia = sidx[i], ib = sidx[p];
                    bool first = (va > vb) || (va == vb && ia < ib);
                    bool up = (i & k) == 0;
                    if (up ? !first : first) {
                        val[i] = vb; val[p] = va; sidx[i] = ib; sidx[p] = ia;
                    }
                }
            }
        __syncthreads();
        // sequential-equivalent greedy scan by wave 0
        if (tid < 64) {
            const int lane = tid;
            int cyc = 0;
            int assigned = assignedS;
            for (int chunk = 0; chunk < 64; ++chunk) {
                if (cyc >= 256 || assigned >= 1024) break;   // uniform
                int i = (chunk << 6) | lane;
                int id = sidx[i];
                int b = id >> 3, j = id & 7;
                unsigned d = Dls[b];
                bool notA = ((d >> j) & 1) == 0;
                int ecj = ec[j];
                int scb = __popc(d & 255);
                // same-b mask via 9 bit-ballots, same-j via 3
                unsigned long long sb = ~0ull;
                #pragma unroll
                for (int t2 = 0; t2 < 9; ++t2) {
                    unsigned long long bl = __ballot((b >> t2) & 1);
                    sb &= ((b >> t2) & 1) ? bl : ~bl;
                }
                unsigned long long jb0 = __ballot(j & 1);
                unsigned long long jb1 = __ballot((j >> 1) & 1);
                unsigned long long jb2 = __ballot((j >> 2) & 1);
                unsigned long long sj = ((j & 1) ? jb0 : ~jb0) &
                                        ((j & 2) ? jb1 : ~jb1) &
                                        ((j & 4) ? jb2 : ~jb2);
                unsigned long long earlier = (1ull << lane) - 1ull;
                bool ok = notA && (ecj < 160) && (scb < 2);
                unsigned long long okm = __ballot(ok);
                // fixed point: lane i depends only on lanes < i -> unique solution
                for (int it = 0; it < 64; ++it) {
                    unsigned long long em = okm & earlier;
                    int aE = __popcll(em & sj);
                    int aS = __popcll(em & sb);
                    int aC = __popcll(em);
                    bool ok2 = notA && (ecj + aE) < 160 && (scb + aS) < 2 &&
                               (cyc + aC) < 256 && (assigned + aC) < 1024;
                    unsigned long long okm2 = __ballot(ok2);
                    ok = ok2;
                    if (okm2 == okm) break;
                    okm = okm2;
                }
                // commit
                int add = __popcll(okm);
                if (lane < 8) {
                    unsigned long long mj = ((lane & 1) ? jb0 : ~jb0) &
                                            ((lane & 2) ? jb1 : ~jb1) &
                                            ((lane & 4) ? jb2 : ~jb2);
                    int c2 = __popcll(mj & okm);
                    if (c2) ec[lane] += c2;
                }
                if (ok) {
                    unsigned long long grp = okm & sb;      // ok lanes sharing my b
                    if (lane == __builtin_ctzll(grp)) {     // leader writes OR of bits
                        unsigned orb = 0;
                        #pragma unroll
                        for (int jj = 0; jj < 8; ++jj) {
                            unsigned long long mj2 = ((jj & 1) ? jb0 : ~jb0) &
                                                     ((jj & 2) ? jb1 : ~jb1) &
                                                     ((jj & 4) ? jb2 : ~jb2);
                            if (mj2 & grp) orb |= (1u << jj);
                        }
                        Dls[b] = (unsigned char)(d | orb);
                    }
                }
                cyc += add;
                assigned += add;
                __threadfence_block();   // LDS writes visible before next chunk reads
            }
            if (lane == 0) assignedS = assigned;
        }
        __syncthreads();
    }

    // final = einsum(w, logits)/norm ; also emit conf and D
    for (int o = tid; o < 5120; o += 1024) {
        int b = o / 10, c = o - b * 10;
        unsigned d = Dls[b];
        float norm = fmaxf((float)__popc(d & 255), 1.0f);
        float sum = 0.f;
        #pragma unroll
        for (int e = 0; e < 8; ++e)
            if ((d >> e) & 1)
                sum += confG[b * 8 + e] * logitsG[(b * 8 + e) * 10 + c];
        outv[o] = sum / norm;
    }
    for (int t = tid; t < 4096; t += 1024) {
        outv[5120 + t] = confG[t];
        outv[9216 + t] = (float)((Dls[t >> 3] >> (t & 7)) & 1);
    }
}

// ============================ launch ============================
extern "C" void kernel_launch(void* const* d_in, const int* in_sizes, int n_in,
                              void* d_out, int out_size, void* d_ws, size_t ws_size,
                              hipStream_t stream)
{
    const float* x    = (const float*)d_in[0];
    const float* w0   = (const float*)d_in[1];
    const float* b0   = (const float*)d_in[2];
    const float* g0   = (const float*)d_in[3];
    const float* bt0  = (const float*)d_in[4];
    const float* rm0  = (const float*)d_in[5];
    const float* rv0  = (const float*)d_in[6];
    const float* w1   = (const float*)d_in[7];
    const float* b1   = (const float*)d_in[8];
    const float* g1   = (const float*)d_in[9];
    const float* bt1  = (const float*)d_in[10];
    const float* rm1  = (const float*)d_in[11];
    const float* rv1  = (const float*)d_in[12];
    const float* w2   = (const float*)d_in[13];
    const float* b2   = (const float*)d_in[14];
    const float* g2   = (const float*)d_in[15];
    const float* bt2  = (const float*)d_in[16];
    const float* rm2  = (const float*)d_in[17];
    const float* rv2  = (const float*)d_in[18];
    const float* w3   = (const float*)d_in[19];
    const float* b3   = (const float*)d_in[20];
    const float* g3   = (const float*)d_in[21];
    const float* bt3  = (const float*)d_in[22];
    const float* rm3  = (const float*)d_in[23];
    const float* rv3  = (const float*)d_in[24];
    const float* cls_w = (const float*)d_in[25];
    const float* cls_b = (const float*)d_in[26];
    float* outp = (float*)d_out;

    char* ws = (char*)d_ws;
    float* act0   = (float*)(ws);                          // 67,108,864 B [512,32,32,32]
    float* act1   = (float*)(ws + 67108864);               // 33,554,432 B [512,64,16,16]
    float* act2   = act0;                                  // reuse: act0 dead after L1
    float* feats  = (float*)(ws + 100663296);              //    524,288 B [512,256]
    float* logits = (float*)(ws + 101187584);              //    163,840 B [512,80]
    float* conf   = (float*)(ws + 101351424);              //     16,384 B [512,8]

    conv0_kernel<<<2048, 256, 0, stream>>>(x, w0, b0, g0, bt0, rm0, rv0, act0);
    convT_kernel<32, 64, 32, 32, true, false>
        <<<1024, 256, 0, stream>>>(act0, w1, b1, g1, bt1, rm1, rv1, act1);
    convT_kernel<64, 128, 16, 32, false, false>
        <<<512, 256, 0, stream>>>(act1, w2, b2, g2, bt2, rm2, rv2, act2);
    convT_kernel<128, 256, 16, 32, true, true>
        <<<1024, 256, 0, stream>>>(act2, w3, b3, g3, bt3, rm3, rv3, feats);
    head_kernel<<<512, 128, 0, stream>>>(feats, cls_w, cls_b, logits, conf);
    route_kernel<<<1, 1024, 0, stream>>>(conf, logits, outp);
}

// Round 2
// 1473.575 us; speedup vs baseline: 3.0208x; 3.0208x over previous
//
#include <hip/hip_runtime.h>
#include <cstdint>
#include <cstddef>

#define EPSV 1e-5f

// ================= K0: conv 3->32, 32x32, BN+ReLU =================
__global__ __launch_bounds__(256) void conv0_kernel(
    const float* __restrict__ x, const float* __restrict__ w,
    const float* __restrict__ bias, const float* __restrict__ g,
    const float* __restrict__ bt, const float* __restrict__ rm,
    const float* __restrict__ rv, float* __restrict__ out)
{
    const int blk = blockIdx.x;            // 2048 blocks
    const int img = blk >> 2;
    const int p = ((blk & 3) << 8) | (int)threadIdx.x;   // pixel 0..1023
    const int y = p >> 5, xx = p & 31;
    const float* xin = x + (size_t)img * 3 * 1024;
    float xv[3][9];
    #pragma unroll
    for (int ci = 0; ci < 3; ++ci)
      #pragma unroll
      for (int ky = 0; ky < 3; ++ky)
        #pragma unroll
        for (int kx = 0; kx < 3; ++kx) {
            int yy = y + ky - 1, xc = xx + kx - 1;
            bool v = (yy >= 0) && (yy < 32) && (xc >= 0) && (xc < 32);
            xv[ci][ky*3+kx] = v ? xin[ci*1024 + yy*32 + xc] : 0.0f;
        }
    float* ob = out + (size_t)img * 32 * 1024 + p;
    #pragma unroll 4
    for (int co = 0; co < 32; ++co) {
        float s = g[co] / sqrtf(rv[co] + EPSV);
        float c = (bias[co] - rm[co]) * s + bt[co];
        float acc = 0.f;
        #pragma unroll
        for (int ci = 0; ci < 3; ++ci)
          #pragma unroll
          for (int k = 0; k < 9; ++k)
            acc += w[(co*3 + ci)*9 + k] * xv[ci][k];
        float v = acc * s + c;
        ob[co*1024] = v > 0.f ? v : 0.f;
    }
}

// ========== Templated conv+BN+ReLU (+pool) (+avg->feats) ==========
// thread = 2x2 output patch; co-tile = COT (16: acc=64 regs, NO spill);
// per-ci input plane staged in LDS with zero ring.
template<int CIN, int COUT, int HW, int COT, bool POOL, bool AVG>
__global__ __launch_bounds__(256, 2) void convT_kernel(
    const float* __restrict__ x, const float* __restrict__ w,
    const float* __restrict__ bias, const float* __restrict__ g,
    const float* __restrict__ bt, const float* __restrict__ rm,
    const float* __restrict__ rv, float* __restrict__ out)
{
    constexpr int PH = HW / 2;
    constexpr int PATCHES = PH * PH;       // threads (patches) per image
    constexpr int IMGS = 256 / PATCHES;    // 1 (HW=32) or 4 (HW=16)
    constexpr int LW = HW + 2;
    constexpr int NZ = COUT / COT;
    __shared__ float plane[IMGS][LW * LW];

    const int imgGroup = blockIdx.x / NZ;
    const int coBase = (blockIdx.x % NZ) * COT;
    const int wave = (int)threadIdx.x >> 6;
    const int img = (IMGS == 1) ? imgGroup : imgGroup * IMGS + wave;
    const int patch = (IMGS == 1) ? (int)threadIdx.x : ((int)threadIdx.x & 63);
    const int py = patch / PH, px = patch % PH;
    const int oy = py * 2, ox = px * 2;

    // zero whole LDS (ring stays zero; interior overwritten each ci)
    for (int t = threadIdx.x; t < IMGS * LW * LW; t += 256)
        (&plane[0][0])[t] = 0.f;

    const float* xin = x + (size_t)img * CIN * HW * HW;
    float* myp = &plane[(IMGS == 1) ? 0 : wave][0];

    float acc[COT][4];   // COT=16 -> 64 VGPRs, register-resident
    #pragma unroll
    for (int co = 0; co < COT; ++co)
      #pragma unroll
      for (int q = 0; q < 4; ++q) acc[co][q] = 0.f;

    float pre[4];
    #pragma unroll
    for (int q = 0; q < 4; ++q) pre[q] = xin[patch + q * PATCHES];

    for (int ci = 0; ci < CIN; ++ci) {
        __syncthreads();                    // prior reads done (or zero-fill done)
        #pragma unroll
        for (int q = 0; q < 4; ++q) {
            int pix = patch + q * PATCHES;
            int yy = pix / HW, xc = pix % HW;
            myp[(yy + 1) * LW + (xc + 1)] = pre[q];
        }
        __syncthreads();
        if (ci + 1 < CIN) {                 // register prefetch of next plane
            const float* nx = xin + (size_t)(ci + 1) * HW * HW;
            #pragma unroll
            for (int q = 0; q < 4; ++q) pre[q] = nx[patch + q * PATCHES];
        }
        float xv[4][4];
        #pragma unroll
        for (int dy = 0; dy < 4; ++dy)
          #pragma unroll
          for (int dx = 0; dx < 4; ++dx)
            xv[dy][dx] = myp[(oy + dy) * LW + ox + dx];
        const float* wci = w + ((size_t)coBase * CIN + ci) * 9;
        #pragma unroll
        for (int co = 0; co < COT; ++co) {
            const float* wp = wci + (size_t)co * CIN * 9;   // wave-uniform -> s_load
            float w0=wp[0],w1=wp[1],w2=wp[2],w3=wp[3],w4=wp[4],
                  w5=wp[5],w6=wp[6],w7=wp[7],w8=wp[8];
            #pragma unroll
            for (int pq = 0; pq < 4; ++pq) {
                int ry = pq >> 1, rx = pq & 1;
                float a = acc[co][pq];
                a += w0*xv[ry][rx];   a += w1*xv[ry][rx+1];   a += w2*xv[ry][rx+2];
                a += w3*xv[ry+1][rx]; a += w4*xv[ry+1][rx+1]; a += w5*xv[ry+1][rx+2];
                a += w6*xv[ry+2][rx]; a += w7*xv[ry+2][rx+1]; a += w8*xv[ry+2][rx+2];
                acc[co][pq] = a;
            }
        }
    }

    #pragma unroll
    for (int co = 0; co < COT; ++co) {
        const int coG = coBase + co;
        float s = g[coG] / sqrtf(rv[coG] + EPSV);
        float c = (bias[coG] - rm[coG]) * s + bt[coG];
        float v0 = acc[co][0]*s + c; v0 = v0 > 0.f ? v0 : 0.f;
        float v1 = acc[co][1]*s + c; v1 = v1 > 0.f ? v1 : 0.f;
        float v2 = acc[co][2]*s + c; v2 = v2 > 0.f ? v2 : 0.f;
        float v3 = acc[co][3]*s + c; v3 = v3 > 0.f ? v3 : 0.f;
        if constexpr (!POOL) {
            float* ob = out + ((size_t)img * COUT + coG) * HW * HW;
            ob[(oy    )*HW + ox    ] = v0;
            ob[(oy    )*HW + ox + 1] = v1;
            ob[(oy + 1)*HW + ox    ] = v2;
            ob[(oy + 1)*HW + ox + 1] = v3;
        } else {
            float m = fmaxf(fmaxf(v0, v1), fmaxf(v2, v3));
            if constexpr (!AVG) {
                out[((size_t)img * COUT + coG) * PH * PH + py * PH + px] = m;
            } else {
                float sum = m;                        // mean over 8x8 pooled = 64 lanes
                #pragma unroll
                for (int off = 32; off >= 1; off >>= 1)
                    sum += __shfl_xor(sum, off, 64);
                if ((threadIdx.x & 63) == 0)
                    out[(size_t)img * COUT + coG] = sum * (1.0f / 64.0f);
            }
        }
    }
}

// ============== K4: head GEMM + log-softmax + conf ==============
__global__ __launch_bounds__(128) void head_kernel(
    const float* __restrict__ feats, const float* __restrict__ cls_w,
    const float* __restrict__ cls_b, float* __restrict__ logits,
    float* __restrict__ conf)
{
    __shared__ float f[256];
    __shared__ float wt[80 * 65];   // +1 pad breaks 64-stride bank conflict
    __shared__ float lg[80];
    const int b = blockIdx.x, tid = (int)threadIdx.x;
    f[tid] = feats[b * 256 + tid];
    f[tid + 128] = feats[b * 256 + tid + 128];
    float acc = 0.f;
    for (int ch = 0; ch < 4; ++ch) {
        __syncthreads();
        for (int q = tid; q < 80 * 64; q += 128) {
            int r = q >> 6, cc = q & 63;
            wt[r * 65 + cc] = cls_w[r * 256 + ch * 64 + cc];
        }
        __syncthreads();
        if (tid < 80) {
            #pragma unroll 8
            for (int dd = 0; dd < 64; ++dd)
                acc += wt[tid * 65 + dd] * f[ch * 64 + dd];
        }
    }
    if (tid < 80) {
        acc += cls_b[tid];
        logits[b * 80 + tid] = acc;
        lg[tid] = acc;
    }
    __syncthreads();
    if (tid < 80 && (tid % 10) == 0) {
        const int e = tid / 10;
        float m = lg[e * 10];
        for (int cc = 1; cc < 10; ++cc) m = fmaxf(m, lg[e * 10 + cc]);
        float ssum = 0.f;
        for (int cc = 0; cc < 10; ++cc) ssum += expf(lg[e * 10 + cc] - m);
        float lz = m + logf(ssum);
        float cf = 0.f;
        for (int cc = 0; cc < 10; ++cc) {
            float lp = lg[e * 10 + cc] - lz;
            cf += expf(lp) * lp;
        }
        conf[b * 8 + e] = cf;
    }
}

// ======= K5: routing (4x [rescale -> bitonic sort -> greedy scan]) + final =======
__global__ __launch_bounds__(1024) void route_kernel(
    const float* __restrict__ confG,   // [512*8]
    const float* __restrict__ logitsG, // [512*80]
    float* __restrict__ outv)          // [5120 final | 4096 conf | 4096 D]
{
    __shared__ float val[4096];
    __shared__ unsigned short sidx[4096];
    __shared__ unsigned char Dls[512];
    __shared__ int ec[8];
    __shared__ int assignedS;
    const int tid = (int)threadIdx.x;
    if (tid < 512) Dls[tid] = 0;
    if (tid < 8) ec[tid] = 0;
    if (tid == 0) assignedS = 0;
    __syncthreads();

    for (int cycle = 0; cycle < 4; ++cycle) {
        // keys: current = conf * (1 - ec/CAP)   (cycle 0: ec=0 -> conf*1.0 bitwise)
        for (int t = tid; t < 4096; t += 1024) {
            float sc = 1.0f - ((float)ec[t & 7]) / 160.0f;
            val[t] = confG[t] * sc;
            sidx[t] = (unsigned short)t;
        }
        // bitonic sort: descending val, ascending idx on ties == stable argsort(-x)
        for (int k = 2; k <= 4096; k <<= 1)
            for (int j = k >> 1; j > 0; j >>= 1) {
                __syncthreads();
                for (int t = tid; t < 2048; t += 1024) {
                    int i = ((t & ~(j - 1)) << 1) | (t & (j - 1));
                    int p = i | j;
                    float va = val[i], vb = val[p];
                    unsigned short ia = sidx[i], ib = sidx[p];
                    bool first = (va > vb) || (va == vb && ia < ib);
                    bool up = (i & k) == 0;
                    if (up ? !first : first) {
                        val[i] = vb; val[p] = va; sidx[i] = ib; sidx[p] = ia;
                    }
                }
            }
        __syncthreads();
        // sequential-equivalent greedy scan by wave 0
        if (tid < 64) {
            const int lane = tid;
            int cyc = 0;
            int assigned = assignedS;
            for (int chunk = 0; chunk < 64; ++chunk) {
                if (cyc >= 256 || assigned >= 1024) break;   // uniform
                int i = (chunk << 6) | lane;
                int id = sidx[i];
                int b = id >> 3, j = id & 7;
                unsigned d = Dls[b];
                bool notA = ((d >> j) & 1) == 0;
                int ecj = ec[j];
                int scb = __popc(d & 255);
                // same-b mask via 9 bit-ballots, same-j via 3
                unsigned long long sb = ~0ull;
                #pragma unroll
                for (int t2 = 0; t2 < 9; ++t2) {
                    unsigned long long bl = __ballot((b >> t2) & 1);
                    sb &= ((b >> t2) & 1) ? bl : ~bl;
                }
                unsigned long long jb0 = __ballot(j & 1);
                unsigned long long jb1 = __ballot((j >> 1) & 1);
                unsigned long long jb2 = __ballot((j >> 2) & 1);
                unsigned long long sj = ((j & 1) ? jb0 : ~jb0) &
                                        ((j & 2) ? jb1 : ~jb1) &
                                        ((j & 4) ? jb2 : ~jb2);
                unsigned long long earlier = (1ull << lane) - 1ull;
                bool ok = notA && (ecj < 160) && (scb < 2);
                unsigned long long okm = __ballot(ok);
                // fixed point: lane i depends only on lanes < i -> unique solution
                for (int it = 0; it < 64; ++it) {
                    unsigned long long em = okm & earlier;
                    int aE = __popcll(em & sj);
                    int aS = __popcll(em & sb);
                    int aC = __popcll(em);
                    bool ok2 = notA && (ecj + aE) < 160 && (scb + aS) < 2 &&
                               (cyc + aC) < 256 && (assigned + aC) < 1024;
                    unsigned long long okm2 = __ballot(ok2);
                    ok = ok2;
                    if (okm2 == okm) break;
                    okm = okm2;
                }
                // commit
                int add = __popcll(okm);
                if (lane < 8) {
                    unsigned long long mj = ((lane & 1) ? jb0 : ~jb0) &
                                            ((lane & 2) ? jb1 : ~jb1) &
                                            ((lane & 4) ? jb2 : ~jb2);
                    int c2 = __popcll(mj & okm);
                    if (c2) ec[lane] += c2;
                }
                if (ok) {
                    unsigned long long grp = okm & sb;      // ok lanes sharing my b
                    if (lane == __builtin_ctzll(grp)) {     // leader writes OR of bits
                        unsigned orb = 0;
                        #pragma unroll
                        for (int jj = 0; jj < 8; ++jj) {
                            unsigned long long mj2 = ((jj & 1) ? jb0 : ~jb0) &
                                                     ((jj & 2) ? jb1 : ~jb1) &
                                                     ((jj & 4) ? jb2 : ~jb2);
                            if (mj2 & grp) orb |= (1u << jj);
                        }
                        Dls[b] = (unsigned char)(d | orb);
                    }
                }
                cyc += add;
                assigned += add;
                __threadfence_block();   // LDS writes visible before next chunk reads
            }
            if (lane == 0) assignedS = assigned;
        }
        __syncthreads();
    }

    // final = einsum(w, logits)/norm ; also emit conf and D
    for (int o = tid; o < 5120; o += 1024) {
        int b = o / 10, c = o - b * 10;
        unsigned d = Dls[b];
        float norm = fmaxf((float)__popc(d & 255), 1.0f);
        float sum = 0.f;
        #pragma unroll
        for (int e = 0; e < 8; ++e)
            if ((d >> e) & 1)
                sum += confG[b * 8 + e] * logitsG[(b * 8 + e) * 10 + c];
        outv[o] = sum / norm;
    }
    for (int t = tid; t < 4096; t += 1024) {
        outv[5120 + t] = confG[t];
        outv[9216 + t] = (float)((Dls[t >> 3] >> (t & 7)) & 1);
    }
}

// ============================ launch ============================
extern "C" void kernel_launch(void* const* d_in, const int* in_sizes, int n_in,
                              void* d_out, int out_size, void* d_ws, size_t ws_size,
                              hipStream_t stream)
{
    const float* x    = (const float*)d_in[0];
    const float* w0   = (const float*)d_in[1];
    const float* b0   = (const float*)d_in[2];
    const float* g0   = (const float*)d_in[3];
    const float* bt0  = (const float*)d_in[4];
    const float* rm0  = (const float*)d_in[5];
    const float* rv0  = (const float*)d_in[6];
    const float* w1   = (const float*)d_in[7];
    const float* b1   = (const float*)d_in[8];
    const float* g1   = (const float*)d_in[9];
    const float* bt1  = (const float*)d_in[10];
    const float* rm1  = (const float*)d_in[11];
    const float* rv1  = (const float*)d_in[12];
    const float* w2   = (const float*)d_in[13];
    const float* b2   = (const float*)d_in[14];
    const float* g2   = (const float*)d_in[15];
    const float* bt2  = (const float*)d_in[16];
    const float* rm2  = (const float*)d_in[17];
    const float* rv2  = (const float*)d_in[18];
    const float* w3   = (const float*)d_in[19];
    const float* b3   = (const float*)d_in[20];
    const float* g3   = (const float*)d_in[21];
    const float* bt3  = (const float*)d_in[22];
    const float* rm3  = (const float*)d_in[23];
    const float* rv3  = (const float*)d_in[24];
    const float* cls_w = (const float*)d_in[25];
    const float* cls_b = (const float*)d_in[26];
    float* outp = (float*)d_out;

    char* ws = (char*)d_ws;
    float* act0   = (float*)(ws);                          // 67,108,864 B [512,32,32,32]
    float* act1   = (float*)(ws + 67108864);               // 33,554,432 B [512,64,16,16]
    float* act2   = act0;                                  // reuse: act0 dead after L1
    float* feats  = (float*)(ws + 100663296);              //    524,288 B [512,256]
    float* logits = (float*)(ws + 101187584);              //    163,840 B [512,80]
    float* conf   = (float*)(ws + 101351424);              //     16,384 B [512,8]

    conv0_kernel<<<2048, 256, 0, stream>>>(x, w0, b0, g0, bt0, rm0, rv0, act0);
    convT_kernel<32, 64, 32, 16, true, false>
        <<<2048, 256, 0, stream>>>(act0, w1, b1, g1, bt1, rm1, rv1, act1);
    convT_kernel<64, 128, 16, 16, false, false>
        <<<1024, 256, 0, stream>>>(act1, w2, b2, g2, bt2, rm2, rv2, act2);
    convT_kernel<128, 256, 16, 16, true, true>
        <<<2048, 256, 0, stream>>>(act2, w3, b3, g3, bt3, rm3, rv3, feats);
    head_kernel<<<512, 128, 0, stream>>>(feats, cls_w, cls_b, logits, conf);
    route_kernel<<<1, 1024, 0, stream>>>(conf, logits, outp);
}

// Round 4
// 726.629 us; speedup vs baseline: 6.1261x; 2.0280x over previous
//
#include <hip/hip_runtime.h>
#include <hip/hip_bf16.h>
#include <cstdint>
#include <cstddef>

#define EPSV 1e-5f
typedef unsigned short u16;
using short8 = __attribute__((ext_vector_type(8))) short;
using f32x4  = __attribute__((ext_vector_type(4))) float;

typedef __attribute__((address_space(1))) void* gp1;
typedef __attribute__((address_space(3))) void* lp3;

__device__ __forceinline__ void gload16(const void* g, void* l) {
    __builtin_amdgcn_global_load_lds((gp1)(void*)g, (lp3)l, 16, 0, 0);
}
__device__ __forceinline__ u16 f2bf(float v) {
    __hip_bfloat16 h = __float2bfloat16(v);
    return *reinterpret_cast<u16*>(&h);
}
__device__ __forceinline__ float bf2f(u16 u) {
    __hip_bfloat16 h; *reinterpret_cast<u16*>(&h) = u;
    return __bfloat162float(h);
}

// ============ ring zero: zero the 1-px border of padded NHWC bf16 planes ============
template<int PH2, int PW2, int C>
__global__ __launch_bounds__(256) void ring_kernel(u16* __restrict__ bh, u16* __restrict__ bl)
{
    constexpr int RN = 2 * PW2 + 2 * (PH2 - 2);
    constexpr int C8 = C / 8;
    int id = blockIdx.x * 256 + (int)threadIdx.x;
    if (id >= 512 * RN * C8) return;
    int c8 = id % C8; int t = id / C8;
    int rp = t % RN;  int im = t / RN;
    int py, px;
    if (rp < PW2)            { py = 0;       px = rp; }
    else if (rp < 2 * PW2)   { py = PH2 - 1; px = rp - PW2; }
    else { int rr = rp - 2 * PW2; py = 1 + (rr >> 1); px = (rr & 1) ? (PW2 - 1) : 0; }
    size_t off = ((size_t)(im * PH2 + py) * PW2 + px) * C + c8 * 8;
    uint4 z = {0u, 0u, 0u, 0u};
    *(uint4*)(bh + off) = z;
    *(uint4*)(bl + off) = z;
}

// ============ weight prep: fold BN scale, transpose to [9][Cout][Cin], split bf16 ============
template<int CIN, int COUT>
__global__ __launch_bounds__(256) void wprep_kernel(
    const float* __restrict__ w, const float* __restrict__ b,
    const float* __restrict__ g, const float* __restrict__ bt,
    const float* __restrict__ rm, const float* __restrict__ rv,
    u16* __restrict__ WH, u16* __restrict__ WL, float* __restrict__ bias)
{
    int id = blockIdx.x * 256 + (int)threadIdx.x;
    if (id >= CIN * COUT) return;
    int co = id / CIN, ci = id % CIN;
    float s = g[co] / sqrtf(rv[co] + EPSV);
    #pragma unroll
    for (int k = 0; k < 9; ++k) {
        float v = w[((size_t)co * CIN + ci) * 9 + k] * s;
        u16 hh = f2bf(v);
        size_t o = ((size_t)k * COUT + co) * CIN + ci;
        WH[o] = hh;
        WL[o] = f2bf(v - bf2f(hh));
    }
    if (ci == 0) bias[co] = (b[co] - rm[co]) * s + bt[co];
}

// ============ conv0: 3->32, fp32 vector math, out = padded NHWC split-bf16 ============
__global__ __launch_bounds__(256) void conv0_kernel(
    const float* __restrict__ x, const float* __restrict__ w,
    const float* __restrict__ bias, const float* __restrict__ g,
    const float* __restrict__ bt, const float* __restrict__ rm,
    const float* __restrict__ rv, u16* __restrict__ Oh, u16* __restrict__ Ol)
{
    const int blk = blockIdx.x;            // 2048 blocks
    const int img = blk >> 2;
    const int p = ((blk & 3) << 8) | (int)threadIdx.x;   // pixel 0..1023
    const int y = p >> 5, xx = p & 31;
    const float* xin = x + (size_t)img * 3 * 1024;
    float xv[3][9];
    #pragma unroll
    for (int ci = 0; ci < 3; ++ci)
      #pragma unroll
      for (int ky = 0; ky < 3; ++ky)
        #pragma unroll
        for (int kx = 0; kx < 3; ++kx) {
            int yy = y + ky - 1, xc = xx + kx - 1;
            bool v = (yy >= 0) && (yy < 32) && (xc >= 0) && (xc < 32);
            xv[ci][ky * 3 + kx] = v ? xin[ci * 1024 + yy * 32 + xc] : 0.0f;
        }
    union { u16 u[32]; uint4 v4[4]; } oh, ol;
    #pragma unroll
    for (int co = 0; co < 32; ++co) {
        float s = g[co] / sqrtf(rv[co] + EPSV);
        float c = (bias[co] - rm[co]) * s + bt[co];
        float acc = 0.f;
        #pragma unroll
        for (int ci = 0; ci < 3; ++ci)
          #pragma unroll
          for (int k = 0; k < 9; ++k)
            acc += w[(co * 3 + ci) * 9 + k] * xv[ci][k];
        float v = acc * s + c;
        v = v > 0.f ? v : 0.f;
        u16 hh = f2bf(v);
        oh.u[co] = hh;
        ol.u[co] = f2bf(v - bf2f(hh));
    }
    size_t po = ((size_t)(img * 34 + y + 1) * 34 + xx + 1) * 32;
    #pragma unroll
    for (int q = 0; q < 4; ++q) {
        ((uint4*)(Oh + po))[q] = oh.v4[q];
        ((uint4*)(Ol + po))[q] = ol.v4[q];
    }
}

// ============ MFMA conv: shift-and-GEMM, split-bf16, padded NHWC in/out ============
// MODE 0: store padded NHWC (conv2). MODE 1: maxpool2 + store padded NHWC (conv1).
// MODE 2: maxpool2 + avgpool -> featsPart[2][512][256] (conv3).
template<int CIN, int COUT, int H, int W, int BM, int BN, int MODE>
__global__ __launch_bounds__(256, 2) void convM_kernel(
    const u16* __restrict__ Ah, const u16* __restrict__ Al,
    const u16* __restrict__ Wh, const u16* __restrict__ Wl,
    const float* __restrict__ bias,
    u16* __restrict__ Oh, u16* __restrict__ Ol, float* __restrict__ featsPart)
{
    constexpr int KC = CIN / 32;            // K32 chunks over cin
    constexpr int ROWS = BM / W;            // output rows per block
    constexpr int WM = BM / 64;             // wave grid (WM x WN == 4 waves)
    constexpr int PW = W + 2;
    constexpr int AT = (ROWS + 2) * PW;     // halo-tile pixel positions
    constexpr int ACH = AT * 4;             // 16B chunks per A plane
    constexpr int BCH = BN * 4;             // 16B chunks per B plane
    constexpr int LW2 = (W == 32) ? 5 : 4;
    constexpr int MPI = (H * W) / BM;       // m-blocks per image

    __shared__ u16 lA[2][AT * 32];
    __shared__ u16 lB[2][BN * 32];

    const int tid = (int)threadIdx.x;
    const int lane = tid & 63;
    const int wv = tid >> 6;
    const int wm = (WM == 4) ? wv : (wv >> 1);
    const int wn = (WM == 4) ? 0 : (wv & 1);
    const int l15 = lane & 15, quad = lane >> 4;

    const int mblk = (int)blockIdx.x, nblk = (int)blockIdx.y;
    const int img = mblk / MPI;
    const int y0 = (mblk % MPI) * ROWS;     // first output row (padded coords == same)
    const size_t imgRow = (size_t)img * (H + 2);

    f32x4 acc[4][4];
    f32x4 zz = {0.f, 0.f, 0.f, 0.f};
    #pragma unroll
    for (int i = 0; i < 4; ++i)
      #pragma unroll
      for (int j = 0; j < 4; ++j) acc[i][j] = zz;

    for (int cb = 0; cb < KC; ++cb) {
        __syncthreads();                    // protect lA (readers of prev cb done)
        // ---- stage A halo tile (both planes), rows y0..y0+ROWS+1, full padded width
        #pragma unroll
        for (int it = 0; it < (ACH + 255) / 256; ++it) {
            int id = it * 256 + tid;
            if (id < ACH) {
                int p = id >> 2, s = id & 3;
                int yy = p / PW, xx = p - yy * PW;
                size_t ge = ((imgRow + y0 + yy) * PW + xx) * CIN + cb * 32 + s * 8;
                u16* ld = (u16*)&lA[0][0] + (size_t)(it * 256 + wv * 64) * 8;
                gload16(Ah + ge, ld);
                gload16(Al + ge, ld + AT * 32);
            }
        }
        for (int sh = 0; sh < 9; ++sh) {
            const int ky = sh / 3, kx = sh - 3 * (sh / 3);
            if (sh) __syncthreads();        // protect lB from prev sh readers
            // ---- stage B chunk [32 cin][BN cout] transposed as [n][k] (both planes)
            #pragma unroll
            for (int it = 0; it < (BCH + 255) / 256; ++it) {
                int id = it * 256 + tid;
                if (id < BCH) {
                    int n = id >> 2, s = id & 3;
                    size_t ge = ((size_t)sh * COUT + nblk * BN + n) * CIN + cb * 32 + s * 8;
                    u16* ld = (u16*)&lB[0][0] + (size_t)(it * 256 + wv * 64) * 8;
                    gload16(Wh + ge, ld);
                    gload16(Wl + ge, ld + BN * 32);
                }
            }
            __syncthreads();                // staging landed (barrier drains vmcnt)
            short8 bh[4], bl[4];
            #pragma unroll
            for (int nt = 0; nt < 4; ++nt) {
                int nrow = wn * 64 + nt * 16 + l15;
                bh[nt] = *(const short8*)&lB[0][nrow * 32 + quad * 8];
                bl[nt] = *(const short8*)&lB[1][nrow * 32 + quad * 8];
            }
            #pragma unroll
            for (int mt = 0; mt < 4; ++mt) {
                int p = wm * 64 + mt * 16 + l15;
                int yl = p >> LW2, xl = p & (W - 1);
                int aoff = ((yl + ky) * PW + xl + kx) * 32 + quad * 8;
                short8 ah = *(const short8*)&lA[0][aoff];
                short8 al = *(const short8*)&lA[1][aoff];
                #pragma unroll
                for (int nt = 0; nt < 4; ++nt) {
                    acc[mt][nt] = __builtin_amdgcn_mfma_f32_16x16x32_bf16(ah, bh[nt], acc[mt][nt], 0, 0, 0);
                    acc[mt][nt] = __builtin_amdgcn_mfma_f32_16x16x32_bf16(ah, bl[nt], acc[mt][nt], 0, 0, 0);
                    acc[mt][nt] = __builtin_amdgcn_mfma_f32_16x16x32_bf16(al, bh[nt], acc[mt][nt], 0, 0, 0);
                }
            }
        }
    }

    // ---- epilogue.  C/D layout: n = lane&15, m(pixel) = mt*16 + quad*4 + reg
    if constexpr (MODE == 0) {
        #pragma unroll
        for (int mt = 0; mt < 4; ++mt) {
            int pbase = wm * 64 + mt * 16 + quad * 4;
            int yy = pbase >> LW2;          // block-local row
            #pragma unroll
            for (int nt = 0; nt < 4; ++nt) {
                int n = nblk * BN + wn * 64 + nt * 16 + l15;
                float bs = bias[n];
                #pragma unroll
                for (int r = 0; r < 4; ++r) {
                    int xx = (pbase & (W - 1)) + r;
                    float v = acc[mt][nt][r] + bs; v = v > 0.f ? v : 0.f;
                    // FIX (R3 bug): global row = y0 + yy (+1 for pad). R3 omitted y0,
                    // so both m-blocks wrote rows 1..8 and rows 9..16 stayed poison.
                    size_t oo = ((size_t)(img * (H + 2) + y0 + yy + 1) * (W + 2) + xx + 1) * COUT + n;
                    u16 hh = f2bf(v);
                    Oh[oo] = hh;
                    Ol[oo] = f2bf(v - bf2f(hh));
                }
            }
        }
    } else if constexpr (MODE == 1) {
        // W=32: y-pairs (mt, mt+2); x-half = mt&1. Output padded [18][18][COUT].
        #pragma unroll
        for (int nt = 0; nt < 4; ++nt) {
            int n = nt * 16 + l15;          // BN=64, wn=0, nblk=0
            float bs = bias[n];
            #pragma unroll
            for (int mb = 0; mb < 2; ++mb) {
                #pragma unroll
                for (int xp = 0; xp < 2; ++xp) {
                    float v = fmaxf(fmaxf(acc[mb][nt][2 * xp], acc[mb][nt][2 * xp + 1]),
                                    fmaxf(acc[mb + 2][nt][2 * xp], acc[mb + 2][nt][2 * xp + 1]));
                    v += bs; v = v > 0.f ? v : 0.f;
                    int py = (y0 >> 1) + wm;
                    int px = mb * 8 + quad * 2 + xp;
                    size_t oo = ((size_t)(img * 18 + py + 1) * 18 + px + 1) * COUT + n;
                    u16 hh = f2bf(v);
                    Oh[oo] = hh;
                    Ol[oo] = f2bf(v - bf2f(hh));
                }
            }
        }
    } else {
        // W=16: y-pairs (2mp, 2mp+1). maxpool -> sum -> feats partial (deterministic).
        __shared__ float fbuf[2][128];
        #pragma unroll
        for (int nt = 0; nt < 4; ++nt) {
            float bs = bias[nblk * BN + wn * 64 + nt * 16 + l15];
            float s = 0.f;
            #pragma unroll
            for (int mp = 0; mp < 2; ++mp)
              #pragma unroll
              for (int xp = 0; xp < 2; ++xp) {
                  float v = fmaxf(fmaxf(acc[2 * mp][nt][2 * xp], acc[2 * mp][nt][2 * xp + 1]),
                                  fmaxf(acc[2 * mp + 1][nt][2 * xp], acc[2 * mp + 1][nt][2 * xp + 1]));
                  v += bs; v = v > 0.f ? v : 0.f;
                  s += v;
              }
            s += __shfl_xor(s, 16, 64);
            s += __shfl_xor(s, 32, 64);
            if (quad == 0) fbuf[wm][wn * 64 + nt * 16 + l15] = s;
        }
        __syncthreads();
        if (tid < 128) {
            float f = (fbuf[0][tid] + fbuf[1][tid]) * (1.0f / 64.0f);
            featsPart[((size_t)(mblk % MPI) * 512 + img) * 256 + nblk * BN + tid] = f;
        }
    }
}

// ============== head GEMM + log-softmax + conf ==============
__global__ __launch_bounds__(128) void head_kernel(
    const float* __restrict__ featsPart, const float* __restrict__ cls_w,
    const float* __restrict__ cls_b, float* __restrict__ logits,
    float* __restrict__ conf)
{
    __shared__ float f[256];
    __shared__ float wt[80 * 65];
    __shared__ float lg[80];
    const int b = blockIdx.x, tid = (int)threadIdx.x;
    f[tid]       = featsPart[b * 256 + tid]       + featsPart[131072 + b * 256 + tid];
    f[tid + 128] = featsPart[b * 256 + tid + 128] + featsPart[131072 + b * 256 + tid + 128];
    float acc = 0.f;
    for (int ch = 0; ch < 4; ++ch) {
        __syncthreads();
        for (int q = tid; q < 80 * 64; q += 128) {
            int r = q >> 6, cc = q & 63;
            wt[r * 65 + cc] = cls_w[r * 256 + ch * 64 + cc];
        }
        __syncthreads();
        if (tid < 80) {
            #pragma unroll 8
            for (int dd = 0; dd < 64; ++dd)
                acc += wt[tid * 65 + dd] * f[ch * 64 + dd];
        }
    }
    if (tid < 80) {
        acc += cls_b[tid];
        logits[b * 80 + tid] = acc;
        lg[tid] = acc;
    }
    __syncthreads();
    if (tid < 80 && (tid % 10) == 0) {
        const int e = tid / 10;
        float m = lg[e * 10];
        for (int cc = 1; cc < 10; ++cc) m = fmaxf(m, lg[e * 10 + cc]);
        float ssum = 0.f;
        for (int cc = 0; cc < 10; ++cc) ssum += expf(lg[e * 10 + cc] - m);
        float lz = m + logf(ssum);
        float cf = 0.f;
        for (int cc = 0; cc < 10; ++cc) {
            float lp = lg[e * 10 + cc] - lz;
            cf += expf(lp) * lp;
        }
        conf[b * 8 + e] = cf;
    }
}

// ======= routing (4x [rescale -> bitonic sort -> greedy scan]) + final =======
__global__ __launch_bounds__(1024) void route_kernel(
    const float* __restrict__ confG,   // [512*8]
    const float* __restrict__ logitsG, // [512*80]
    float* __restrict__ outv)          // [5120 final | 4096 conf | 4096 D]
{
    __shared__ float val[4096];
    __shared__ unsigned short sidx[4096];
    __shared__ unsigned char Dls[512];
    __shared__ int ec[8];
    __shared__ int assignedS;
    const int tid = (int)threadIdx.x;
    if (tid < 512) Dls[tid] = 0;
    if (tid < 8) ec[tid] = 0;
    if (tid == 0) assignedS = 0;
    __syncthreads();

    for (int cycle = 0; cycle < 4; ++cycle) {
        for (int t = tid; t < 4096; t += 1024) {
            float sc = 1.0f - ((float)ec[t & 7]) / 160.0f;
            val[t] = confG[t] * sc;
            sidx[t] = (unsigned short)t;
        }
        for (int k = 2; k <= 4096; k <<= 1)
            for (int j = k >> 1; j > 0; j >>= 1) {
                __syncthreads();
                for (int t = tid; t < 2048; t += 1024) {
                    int i = ((t & ~(j - 1)) << 1) | (t & (j - 1));
                    int p = i | j;
                    float va = val[i], vb = val[p];
                    unsigned short ia = sidx[i], ib = sidx[p];
                    bool first = (va > vb) || (va == vb && ia < ib);
                    bool up = (i & k) == 0;
                    if (up ? !first : first) {
                        val[i] = vb; val[p] = va; sidx[i] = ib; sidx[p] = ia;
                    }
                }
            }
        __syncthreads();
        if (tid < 64) {
            const int lane = tid;
            int cyc = 0;
            int assigned = assignedS;
            for (int chunk = 0; chunk < 64; ++chunk) {
                if (cyc >= 256 || assigned >= 1024) break;
                int i = (chunk << 6) | lane;
                int id = sidx[i];
                int b = id >> 3, j = id & 7;
                unsigned d = Dls[b];
                bool notA = ((d >> j) & 1) == 0;
                int ecj = ec[j];
                int scb = __popc(d & 255);
                unsigned long long sb = ~0ull;
                #pragma unroll
                for (int t2 = 0; t2 < 9; ++t2) {
                    unsigned long long bl = __ballot((b >> t2) & 1);
                    sb &= ((b >> t2) & 1) ? bl : ~bl;
                }
                unsigned long long jb0 = __ballot(j & 1);
                unsigned long long jb1 = __ballot((j >> 1) & 1);
                unsigned long long jb2 = __ballot((j >> 2) & 1);
                unsigned long long sj = ((j & 1) ? jb0 : ~jb0) &
                                        ((j & 2) ? jb1 : ~jb1) &
                                        ((j & 4) ? jb2 : ~jb2);
                unsigned long long earlier = (1ull << lane) - 1ull;
                bool ok = notA && (ecj < 160) && (scb < 2);
                unsigned long long okm = __ballot(ok);
                for (int it = 0; it < 64; ++it) {
                    unsigned long long em = okm & earlier;
                    int aE = __popcll(em & sj);
                    int aS = __popcll(em & sb);
                    int aC = __popcll(em);
                    bool ok2 = notA && (ecj + aE) < 160 && (scb + aS) < 2 &&
                               (cyc + aC) < 256 && (assigned + aC) < 1024;
                    unsigned long long okm2 = __ballot(ok2);
                    ok = ok2;
                    if (okm2 == okm) break;
                    okm = okm2;
                }
                int add = __popcll(okm);
                if (lane < 8) {
                    unsigned long long mj = ((lane & 1) ? jb0 : ~jb0) &
                                            ((lane & 2) ? jb1 : ~jb1) &
                                            ((lane & 4) ? jb2 : ~jb2);
                    int c2 = __popcll(mj & okm);
                    if (c2) ec[lane] += c2;
                }
                if (ok) {
                    unsigned long long grp = okm & sb;
                    if (lane == __builtin_ctzll(grp)) {
                        unsigned orb = 0;
                        #pragma unroll
                        for (int jj = 0; jj < 8; ++jj) {
                            unsigned long long mj2 = ((jj & 1) ? jb0 : ~jb0) &
                                                     ((jj & 2) ? jb1 : ~jb1) &
                                                     ((jj & 4) ? jb2 : ~jb2);
                            if (mj2 & grp) orb |= (1u << jj);
                        }
                        Dls[b] = (unsigned char)(d | orb);
                    }
                }
                cyc += add;
                assigned += add;
                __threadfence_block();
            }
            if (lane == 0) assignedS = assigned;
        }
        __syncthreads();
    }

    for (int o = tid; o < 5120; o += 1024) {
        int b = o / 10, c = o - b * 10;
        unsigned d = Dls[b];
        float norm = fmaxf((float)__popc(d & 255), 1.0f);
        float sum = 0.f;
        #pragma unroll
        for (int e = 0; e < 8; ++e)
            if ((d >> e) & 1)
                sum += confG[b * 8 + e] * logitsG[(b * 8 + e) * 10 + c];
        outv[o] = sum / norm;
    }
    for (int t = tid; t < 4096; t += 1024) {
        outv[5120 + t] = confG[t];
        outv[9216 + t] = (float)((Dls[t >> 3] >> (t & 7)) & 1);
    }
}

// ============================ launch ============================
extern "C" void kernel_launch(void* const* d_in, const int* in_sizes, int n_in,
                              void* d_out, int out_size, void* d_ws, size_t ws_size,
                              hipStream_t stream)
{
    const float* x    = (const float*)d_in[0];
    const float* w0   = (const float*)d_in[1];
    const float* b0   = (const float*)d_in[2];
    const float* g0   = (const float*)d_in[3];
    const float* bt0  = (const float*)d_in[4];
    const float* rm0  = (const float*)d_in[5];
    const float* rv0  = (const float*)d_in[6];
    const float* w1   = (const float*)d_in[7];
    const float* b1   = (const float*)d_in[8];
    const float* g1   = (const float*)d_in[9];
    const float* bt1  = (const float*)d_in[10];
    const float* rm1  = (const float*)d_in[11];
    const float* rv1  = (const float*)d_in[12];
    const float* w2   = (const float*)d_in[13];
    const float* b2   = (const float*)d_in[14];
    const float* g2   = (const float*)d_in[15];
    const float* bt2  = (const float*)d_in[16];
    const float* rm2  = (const float*)d_in[17];
    const float* rv2  = (const float*)d_in[18];
    const float* w3   = (const float*)d_in[19];
    const float* b3   = (const float*)d_in[20];
    const float* g3   = (const float*)d_in[21];
    const float* bt3  = (const float*)d_in[22];
    const float* rm3  = (const float*)d_in[23];
    const float* rv3  = (const float*)d_in[24];
    const float* cls_w = (const float*)d_in[25];
    const float* cls_b = (const float*)d_in[26];
    float* outp = (float*)d_out;

    char* ws = (char*)d_ws;
    // act1p: [512][18][18][64] bf16 h/l
    u16* A1H = (u16*)(ws);
    u16* A1L = (u16*)(ws + 21233664);
    // region X (42467328..): act0p h/l during conv0/conv1; act2p h/l after
    u16* A0H = (u16*)(ws + 42467328);
    u16* A0L = (u16*)(ws + 42467328 + 37879808);
    u16* A2H = (u16*)(ws + 42467328);
    u16* A2L = (u16*)(ws + 42467328 + 42467328);
    u16* W1H = (u16*)(ws + 127401984);
    u16* W1L = (u16*)(ws + 127438848);
    u16* W2H = (u16*)(ws + 127475712);
    u16* W2L = (u16*)(ws + 127623168);
    u16* W3H = (u16*)(ws + 127770624);
    u16* W3L = (u16*)(ws + 128360448);
    float* BS1 = (float*)(ws + 128950272);
    float* BS2 = (float*)(ws + 128950528);
    float* BS3 = (float*)(ws + 128951040);
    float* featsPart = (float*)(ws + 128952064);   // [2][512][256]
    float* logits    = (float*)(ws + 130000640);
    float* conf      = (float*)(ws + 130164480);

    // prep: rings + weights (act2p ring deferred: aliases act0p)
    ring_kernel<34, 34, 32><<<(512 * 132 * 4 + 255) / 256, 256, 0, stream>>>(A0H, A0L);
    ring_kernel<18, 18, 64><<<(512 * 68 * 8 + 255) / 256, 256, 0, stream>>>(A1H, A1L);
    wprep_kernel<32, 64><<<8, 256, 0, stream>>>(w1, b1, g1, bt1, rm1, rv1, W1H, W1L, BS1);
    wprep_kernel<64, 128><<<32, 256, 0, stream>>>(w2, b2, g2, bt2, rm2, rv2, W2H, W2L, BS2);
    wprep_kernel<128, 256><<<128, 256, 0, stream>>>(w3, b3, g3, bt3, rm3, rv3, W3H, W3L, BS3);

    conv0_kernel<<<2048, 256, 0, stream>>>(x, w0, b0, g0, bt0, rm0, rv0, A0H, A0L);
    convM_kernel<32, 64, 32, 32, 256, 64, 1>
        <<<dim3(2048, 1), 256, 0, stream>>>(A0H, A0L, W1H, W1L, BS1, A1H, A1L, nullptr);
    ring_kernel<18, 18, 128><<<(512 * 68 * 16 + 255) / 256, 256, 0, stream>>>(A2H, A2L);
    convM_kernel<64, 128, 16, 16, 128, 128, 0>
        <<<dim3(1024, 1), 256, 0, stream>>>(A1H, A1L, W2H, W2L, BS2, A2H, A2L, nullptr);
    convM_kernel<128, 256, 16, 16, 128, 128, 2>
        <<<dim3(1024, 2), 256, 0, stream>>>(A2H, A2L, W3H, W3L, BS3, nullptr, nullptr, featsPart);
    head_kernel<<<512, 128, 0, stream>>>(featsPart, cls_w, cls_b, logits, conf);
    route_kernel<<<1, 1024, 0, stream>>>(conf, logits, outp);
}

// Round 5
// 613.064 us; speedup vs baseline: 7.2609x; 1.1852x over previous
//
#include <hip/hip_runtime.h>
#include <hip/hip_bf16.h>
#include <cstdint>
#include <cstddef>

#define EPSV 1e-5f
typedef unsigned short u16;
using short8 = __attribute__((ext_vector_type(8))) short;
using f32x4  = __attribute__((ext_vector_type(4))) float;

typedef __attribute__((address_space(1))) void* gp1;
typedef __attribute__((address_space(3))) void* lp3;

__device__ __forceinline__ void gload16(const void* g, void* l) {
    __builtin_amdgcn_global_load_lds((gp1)(void*)g, (lp3)l, 16, 0, 0);
}
__device__ __forceinline__ u16 f2bf(float v) {
    __hip_bfloat16 h = __float2bfloat16(v);
    return *reinterpret_cast<u16*>(&h);
}
__device__ __forceinline__ float bf2f(u16 u) {
    __hip_bfloat16 h; *reinterpret_cast<u16*>(&h) = u;
    return __bfloat162float(h);
}

// ============ ring zero: zero the 1-px border of padded NHWC bf16 planes ============
template<int PH2, int PW2, int C>
__global__ __launch_bounds__(256) void ring_kernel(u16* __restrict__ bh, u16* __restrict__ bl)
{
    constexpr int RN = 2 * PW2 + 2 * (PH2 - 2);
    constexpr int C8 = C / 8;
    int id = blockIdx.x * 256 + (int)threadIdx.x;
    if (id >= 512 * RN * C8) return;
    int c8 = id % C8; int t = id / C8;
    int rp = t % RN;  int im = t / RN;
    int py, px;
    if (rp < PW2)            { py = 0;       px = rp; }
    else if (rp < 2 * PW2)   { py = PH2 - 1; px = rp - PW2; }
    else { int rr = rp - 2 * PW2; py = 1 + (rr >> 1); px = (rr & 1) ? (PW2 - 1) : 0; }
    size_t off = ((size_t)(im * PH2 + py) * PW2 + px) * C + c8 * 8;
    uint4 z = {0u, 0u, 0u, 0u};
    *(uint4*)(bh + off) = z;
    *(uint4*)(bl + off) = z;
}

// ============ weight prep: fold BN scale, transpose to [9][Cout][Cin], split bf16 ============
template<int CIN, int COUT>
__global__ __launch_bounds__(256) void wprep_kernel(
    const float* __restrict__ w, const float* __restrict__ b,
    const float* __restrict__ g, const float* __restrict__ bt,
    const float* __restrict__ rm, const float* __restrict__ rv,
    u16* __restrict__ WH, u16* __restrict__ WL, float* __restrict__ bias)
{
    int id = blockIdx.x * 256 + (int)threadIdx.x;
    if (id >= CIN * COUT) return;
    int co = id / CIN, ci = id % CIN;
    float s = g[co] / sqrtf(rv[co] + EPSV);
    #pragma unroll
    for (int k = 0; k < 9; ++k) {
        float v = w[((size_t)co * CIN + ci) * 9 + k] * s;
        u16 hh = f2bf(v);
        size_t o = ((size_t)k * COUT + co) * CIN + ci;
        WH[o] = hh;
        WL[o] = f2bf(v - bf2f(hh));
    }
    if (ci == 0) bias[co] = (b[co] - rm[co]) * s + bt[co];
}

// ============ conv0: 3->32, fp32 vector math, out = padded NHWC split-bf16 ============
__global__ __launch_bounds__(256) void conv0_kernel(
    const float* __restrict__ x, const float* __restrict__ w,
    const float* __restrict__ bias, const float* __restrict__ g,
    const float* __restrict__ bt, const float* __restrict__ rm,
    const float* __restrict__ rv, u16* __restrict__ Oh, u16* __restrict__ Ol)
{
    const int blk = blockIdx.x;            // 2048 blocks
    const int img = blk >> 2;
    const int p = ((blk & 3) << 8) | (int)threadIdx.x;   // pixel 0..1023
    const int y = p >> 5, xx = p & 31;
    const float* xin = x + (size_t)img * 3 * 1024;
    float xv[3][9];
    #pragma unroll
    for (int ci = 0; ci < 3; ++ci)
      #pragma unroll
      for (int ky = 0; ky < 3; ++ky)
        #pragma unroll
        for (int kx = 0; kx < 3; ++kx) {
            int yy = y + ky - 1, xc = xx + kx - 1;
            bool v = (yy >= 0) && (yy < 32) && (xc >= 0) && (xc < 32);
            xv[ci][ky * 3 + kx] = v ? xin[ci * 1024 + yy * 32 + xc] : 0.0f;
        }
    union { u16 u[32]; uint4 v4[4]; } oh, ol;
    #pragma unroll
    for (int co = 0; co < 32; ++co) {
        float s = g[co] / sqrtf(rv[co] + EPSV);
        float c = (bias[co] - rm[co]) * s + bt[co];
        float acc = 0.f;
        #pragma unroll
        for (int ci = 0; ci < 3; ++ci)
          #pragma unroll
          for (int k = 0; k < 9; ++k)
            acc += w[(co * 3 + ci) * 9 + k] * xv[ci][k];
        float v = acc * s + c;
        v = v > 0.f ? v : 0.f;
        u16 hh = f2bf(v);
        oh.u[co] = hh;
        ol.u[co] = f2bf(v - bf2f(hh));
    }
    size_t po = ((size_t)(img * 34 + y + 1) * 34 + xx + 1) * 32;
    #pragma unroll
    for (int q = 0; q < 4; ++q) {
        ((uint4*)(Oh + po))[q] = oh.v4[q];
        ((uint4*)(Ol + po))[q] = ol.v4[q];
    }
}

// ============ MFMA conv: shift-and-GEMM, split-bf16, padded NHWC in/out ============
template<int CIN, int COUT, int H, int W, int BM, int BN, int MODE>
__global__ __launch_bounds__(256, 2) void convM_kernel(
    const u16* __restrict__ Ah, const u16* __restrict__ Al,
    const u16* __restrict__ Wh, const u16* __restrict__ Wl,
    const float* __restrict__ bias,
    u16* __restrict__ Oh, u16* __restrict__ Ol, float* __restrict__ featsPart)
{
    constexpr int KC = CIN / 32;
    constexpr int ROWS = BM / W;
    constexpr int WM = BM / 64;
    constexpr int PW = W + 2;
    constexpr int AT = (ROWS + 2) * PW;
    constexpr int ACH = AT * 4;
    constexpr int BCH = BN * 4;
    constexpr int LW2 = (W == 32) ? 5 : 4;
    constexpr int MPI = (H * W) / BM;

    __shared__ u16 lA[2][AT * 32];
    __shared__ u16 lB[2][BN * 32];

    const int tid = (int)threadIdx.x;
    const int lane = tid & 63;
    const int wv = tid >> 6;
    const int wm = (WM == 4) ? wv : (wv >> 1);
    const int wn = (WM == 4) ? 0 : (wv & 1);
    const int l15 = lane & 15, quad = lane >> 4;

    const int mblk = (int)blockIdx.x, nblk = (int)blockIdx.y;
    const int img = mblk / MPI;
    const int y0 = (mblk % MPI) * ROWS;
    const size_t imgRow = (size_t)img * (H + 2);

    f32x4 acc[4][4];
    f32x4 zz = {0.f, 0.f, 0.f, 0.f};
    #pragma unroll
    for (int i = 0; i < 4; ++i)
      #pragma unroll
      for (int j = 0; j < 4; ++j) acc[i][j] = zz;

    for (int cb = 0; cb < KC; ++cb) {
        __syncthreads();
        #pragma unroll
        for (int it = 0; it < (ACH + 255) / 256; ++it) {
            int id = it * 256 + tid;
            if (id < ACH) {
                int p = id >> 2, s = id & 3;
                int yy = p / PW, xx = p - yy * PW;
                size_t ge = ((imgRow + y0 + yy) * PW + xx) * CIN + cb * 32 + s * 8;
                u16* ld = (u16*)&lA[0][0] + (size_t)(it * 256 + wv * 64) * 8;
                gload16(Ah + ge, ld);
                gload16(Al + ge, ld + AT * 32);
            }
        }
        for (int sh = 0; sh < 9; ++sh) {
            const int ky = sh / 3, kx = sh - 3 * (sh / 3);
            if (sh) __syncthreads();
            #pragma unroll
            for (int it = 0; it < (BCH + 255) / 256; ++it) {
                int id = it * 256 + tid;
                if (id < BCH) {
                    int n = id >> 2, s = id & 3;
                    size_t ge = ((size_t)sh * COUT + nblk * BN + n) * CIN + cb * 32 + s * 8;
                    u16* ld = (u16*)&lB[0][0] + (size_t)(it * 256 + wv * 64) * 8;
                    gload16(Wh + ge, ld);
                    gload16(Wl + ge, ld + BN * 32);
                }
            }
            __syncthreads();
            short8 bh[4], bl[4];
            #pragma unroll
            for (int nt = 0; nt < 4; ++nt) {
                int nrow = wn * 64 + nt * 16 + l15;
                bh[nt] = *(const short8*)&lB[0][nrow * 32 + quad * 8];
                bl[nt] = *(const short8*)&lB[1][nrow * 32 + quad * 8];
            }
            #pragma unroll
            for (int mt = 0; mt < 4; ++mt) {
                int p = wm * 64 + mt * 16 + l15;
                int yl = p >> LW2, xl = p & (W - 1);
                int aoff = ((yl + ky) * PW + xl + kx) * 32 + quad * 8;
                short8 ah = *(const short8*)&lA[0][aoff];
                short8 al = *(const short8*)&lA[1][aoff];
                #pragma unroll
                for (int nt = 0; nt < 4; ++nt) {
                    acc[mt][nt] = __builtin_amdgcn_mfma_f32_16x16x32_bf16(ah, bh[nt], acc[mt][nt], 0, 0, 0);
                    acc[mt][nt] = __builtin_amdgcn_mfma_f32_16x16x32_bf16(ah, bl[nt], acc[mt][nt], 0, 0, 0);
                    acc[mt][nt] = __builtin_amdgcn_mfma_f32_16x16x32_bf16(al, bh[nt], acc[mt][nt], 0, 0, 0);
                }
            }
        }
    }

    if constexpr (MODE == 0) {
        #pragma unroll
        for (int mt = 0; mt < 4; ++mt) {
            int pbase = wm * 64 + mt * 16 + quad * 4;
            int yy = pbase >> LW2;
            #pragma unroll
            for (int nt = 0; nt < 4; ++nt) {
                int n = nblk * BN + wn * 64 + nt * 16 + l15;
                float bs = bias[n];
                #pragma unroll
                for (int r = 0; r < 4; ++r) {
                    int xx = (pbase & (W - 1)) + r;
                    float v = acc[mt][nt][r] + bs; v = v > 0.f ? v : 0.f;
                    size_t oo = ((size_t)(img * (H + 2) + y0 + yy + 1) * (W + 2) + xx + 1) * COUT + n;
                    u16 hh = f2bf(v);
                    Oh[oo] = hh;
                    Ol[oo] = f2bf(v - bf2f(hh));
                }
            }
        }
    } else if constexpr (MODE == 1) {
        #pragma unroll
        for (int nt = 0; nt < 4; ++nt) {
            int n = nt * 16 + l15;
            float bs = bias[n];
            #pragma unroll
            for (int mb = 0; mb < 2; ++mb) {
                #pragma unroll
                for (int xp = 0; xp < 2; ++xp) {
                    float v = fmaxf(fmaxf(acc[mb][nt][2 * xp], acc[mb][nt][2 * xp + 1]),
                                    fmaxf(acc[mb + 2][nt][2 * xp], acc[mb + 2][nt][2 * xp + 1]));
                    v += bs; v = v > 0.f ? v : 0.f;
                    int py = (y0 >> 1) + wm;
                    int px = mb * 8 + quad * 2 + xp;
                    size_t oo = ((size_t)(img * 18 + py + 1) * 18 + px + 1) * COUT + n;
                    u16 hh = f2bf(v);
                    Oh[oo] = hh;
                    Ol[oo] = f2bf(v - bf2f(hh));
                }
            }
        }
    } else {
        __shared__ float fbuf[2][128];
        #pragma unroll
        for (int nt = 0; nt < 4; ++nt) {
            float bs = bias[nblk * BN + wn * 64 + nt * 16 + l15];
            float s = 0.f;
            #pragma unroll
            for (int mp = 0; mp < 2; ++mp)
              #pragma unroll
              for (int xp = 0; xp < 2; ++xp) {
                  float v = fmaxf(fmaxf(acc[2 * mp][nt][2 * xp], acc[2 * mp][nt][2 * xp + 1]),
                                  fmaxf(acc[2 * mp + 1][nt][2 * xp], acc[2 * mp + 1][nt][2 * xp + 1]));
                  v += bs; v = v > 0.f ? v : 0.f;
                  s += v;
              }
            s += __shfl_xor(s, 16, 64);
            s += __shfl_xor(s, 32, 64);
            if (quad == 0) fbuf[wm][wn * 64 + nt * 16 + l15] = s;
        }
        __syncthreads();
        if (tid < 128) {
            float f = (fbuf[0][tid] + fbuf[1][tid]) * (1.0f / 64.0f);
            featsPart[((size_t)(mblk % MPI) * 512 + img) * 256 + nblk * BN + tid] = f;
        }
    }
}

// ============== head GEMM + log-softmax + conf ==============
__global__ __launch_bounds__(128) void head_kernel(
    const float* __restrict__ featsPart, const float* __restrict__ cls_w,
    const float* __restrict__ cls_b, float* __restrict__ logits,
    float* __restrict__ conf)
{
    __shared__ float f[256];
    __shared__ float wt[80 * 65];
    __shared__ float lg[80];
    const int b = blockIdx.x, tid = (int)threadIdx.x;
    f[tid]       = featsPart[b * 256 + tid]       + featsPart[131072 + b * 256 + tid];
    f[tid + 128] = featsPart[b * 256 + tid + 128] + featsPart[131072 + b * 256 + tid + 128];
    float acc = 0.f;
    for (int ch = 0; ch < 4; ++ch) {
        __syncthreads();
        for (int q = tid; q < 80 * 64; q += 128) {
            int r = q >> 6, cc = q & 63;
            wt[r * 65 + cc] = cls_w[r * 256 + ch * 64 + cc];
        }
        __syncthreads();
        if (tid < 80) {
            #pragma unroll 8
            for (int dd = 0; dd < 64; ++dd)
                acc += wt[tid * 65 + dd] * f[ch * 64 + dd];
        }
    }
    if (tid < 80) {
        acc += cls_b[tid];
        logits[b * 80 + tid] = acc;
        lg[tid] = acc;
    }
    __syncthreads();
    if (tid < 80 && (tid % 10) == 0) {
        const int e = tid / 10;
        float m = lg[e * 10];
        for (int cc = 1; cc < 10; ++cc) m = fmaxf(m, lg[e * 10 + cc]);
        float ssum = 0.f;
        for (int cc = 0; cc < 10; ++cc) ssum += expf(lg[e * 10 + cc] - m);
        float lz = m + logf(ssum);
        float cf = 0.f;
        for (int cc = 0; cc < 10; ++cc) {
            float lp = lg[e * 10 + cc] - lz;
            cf += expf(lp) * lp;
        }
        conf[b * 8 + e] = cf;
    }
}

// ======= presort: per-expert descending sort of conf (done ONCE) =======
// block j sorts expert j's 512 values desc (tie: b asc); emits idx = b*8+j.
__global__ __launch_bounds__(256) void presort_kernel(
    const float* __restrict__ confG, u16* __restrict__ sidx0)
{
    __shared__ float v[512];
    __shared__ u16 bi[512];
    const int j = (int)blockIdx.x, tid = (int)threadIdx.x;
    for (int r = tid; r < 512; r += 256) { v[r] = confG[r * 8 + j]; bi[r] = (u16)r; }
    for (int k = 2; k <= 512; k <<= 1)
        for (int jj = k >> 1; jj > 0; jj >>= 1) {
            __syncthreads();
            int i = ((tid & ~(jj - 1)) << 1) | (tid & (jj - 1));
            int p = i | jj;
            float va = v[i], vb = v[p];
            u16 ia = bi[i], ib = bi[p];
            bool first = (va > vb) || (va == vb && ia < ib);
            bool up = (i & k) == 0;
            if (up ? !first : first) { v[i] = vb; v[p] = va; bi[i] = ib; bi[p] = ia; }
        }
    __syncthreads();
    for (int r = tid; r < 512; r += 256)
        sidx0[j * 512 + r] = (u16)(bi[r] * 8 + j);
}

// ======= routing: per cycle [rescale -> 3-level merge-path -> greedy scan] + final =======
__global__ __launch_bounds__(1024) void route_kernel(
    const float* __restrict__ confG,   // [512*8]
    const float* __restrict__ logitsG, // [512*80]
    const u16*   __restrict__ sidx0,   // [4096] presorted per-expert idx lists
    float* __restrict__ outv)          // [5120 final | 4096 conf | 4096 D]
{
    __shared__ float valById[4096];    // conf by flat idx
    __shared__ float sv[4096];         // scaled value by idx (per cycle)
    __shared__ u16 P[4096];            // presorted lists (persist all cycles)
    __shared__ u16 mA[4096];           // merge ping
    __shared__ u16 mB[4096];           // merge pong
    __shared__ unsigned char Dls[512];
    __shared__ int ec[8];
    __shared__ int assignedS;
    const int tid = (int)threadIdx.x;

    for (int t = tid; t < 4096; t += 1024) {
        valById[t] = confG[t];
        P[t] = sidx0[t];
    }
    if (tid < 512) Dls[tid] = 0;
    if (tid < 8) ec[tid] = 0;
    if (tid == 0) assignedS = 0;

    auto earlier = [&](u16 a, u16 b) -> bool {
        float va = sv[a], vb = sv[b];
        return (va > vb) || (va == vb && a < b);
    };
    auto mergeChunk = [&](const u16* X, const u16* Y, int n, int o0, u16* out) {
        int lo = o0 - n; if (lo < 0) lo = 0;
        int hi = o0 < n ? o0 : n;
        while (lo < hi) {
            int mid = (lo + hi) >> 1;
            if (earlier(X[mid], Y[o0 - 1 - mid])) lo = mid + 1; else hi = mid;
        }
        int i = lo, jj = o0 - lo;
        #pragma unroll
        for (int q = 0; q < 4; ++q) {
            u16 xc = X[i < n ? i : (n - 1)];
            u16 yc = Y[jj < n ? jj : (n - 1)];
            bool takeX = (jj >= n) || ((i < n) && earlier(xc, yc));
            out[q] = takeX ? xc : yc;
            if (takeX) ++i; else ++jj;
        }
    };

    for (int cycle = 0; cycle < 4; ++cycle) {
        __syncthreads();                      // ec/valById/P visible
        // rescale: identical float expr to reference: conf * (1 - ec/160)
        for (int t = tid; t < 4096; t += 1024) {
            float sc = 1.0f - ((float)ec[t & 7]) / 160.0f;
            sv[t] = valById[t] * sc;
        }
        __syncthreads();
        {   // L1: P (8 lists of 512) -> mA (4 lists of 1024)
            int g = tid << 2;
            int p = g >> 10, o0 = g & 1023;
            mergeChunk(&P[(p << 1) * 512], &P[(p << 1) * 512 + 512], 512, o0, &mA[(p << 10) + o0]);
        }
        __syncthreads();
        {   // L2: mA -> mB (2 lists of 2048)
            int g = tid << 2;
            int p = g >> 11, o0 = g & 2047;
            mergeChunk(&mA[p << 11], &mA[(p << 11) + 1024], 1024, o0, &mB[(p << 11) + o0]);
        }
        __syncthreads();
        {   // L3: mB -> mA (full 4096 order, descending)
            int o0 = tid << 2;
            mergeChunk(&mB[0], &mB[2048], 2048, o0, &mA[o0]);
        }
        __syncthreads();
        // sequential-equivalent greedy scan by wave 0 (reads mA)
        if (tid < 64) {
            const int lane = tid;
            int cyc = 0;
            int assigned = assignedS;
            for (int chunk = 0; chunk < 64; ++chunk) {
                if (cyc >= 256 || assigned >= 1024) break;
                int id = mA[(chunk << 6) | lane];
                int b = id >> 3, j = id & 7;
                unsigned d = Dls[b];
                bool notA = ((d >> j) & 1) == 0;
                int ecj = ec[j];
                int scb = __popc(d & 255);
                unsigned long long sb = ~0ull;
                #pragma unroll
                for (int t2 = 0; t2 < 9; ++t2) {
                    unsigned long long bl = __ballot((b >> t2) & 1);
                    sb &= ((b >> t2) & 1) ? bl : ~bl;
                }
                unsigned long long jb0 = __ballot(j & 1);
                unsigned long long jb1 = __ballot((j >> 1) & 1);
                unsigned long long jb2 = __ballot((j >> 2) & 1);
                unsigned long long sj = ((j & 1) ? jb0 : ~jb0) &
                                        ((j & 2) ? jb1 : ~jb1) &
                                        ((j & 4) ? jb2 : ~jb2);
                unsigned long long earlierM = (1ull << lane) - 1ull;
                bool ok = notA && (ecj < 160) && (scb < 2);
                unsigned long long okm = __ballot(ok);
                for (int it = 0; it < 64; ++it) {
                    unsigned long long em = okm & earlierM;
                    int aE = __popcll(em & sj);
                    int aS = __popcll(em & sb);
                    int aC = __popcll(em);
                    bool ok2 = notA && (ecj + aE) < 160 && (scb + aS) < 2 &&
                               (cyc + aC) < 256 && (assigned + aC) < 1024;
                    unsigned long long okm2 = __ballot(ok2);
                    ok = ok2;
                    if (okm2 == okm) break;
                    okm = okm2;
                }
                int add = __popcll(okm);
                if (lane < 8) {
                    unsigned long long mj = ((lane & 1) ? jb0 : ~jb0) &
                                            ((lane & 2) ? jb1 : ~jb1) &
                                            ((lane & 4) ? jb2 : ~jb2);
                    int c2 = __popcll(mj & okm);
                    if (c2) ec[lane] += c2;
                }
                if (ok) {
                    unsigned long long grp = okm & sb;
                    if (lane == __builtin_ctzll(grp)) {
                        unsigned orb = 0;
                        #pragma unroll
                        for (int jj2 = 0; jj2 < 8; ++jj2) {
                            unsigned long long mj2 = ((jj2 & 1) ? jb0 : ~jb0) &
                                                     ((jj2 & 2) ? jb1 : ~jb1) &
                                                     ((jj2 & 4) ? jb2 : ~jb2);
                            if (mj2 & grp) orb |= (1u << jj2);
                        }
                        Dls[b] = (unsigned char)(d | orb);
                    }
                }
                cyc += add;
                assigned += add;
                __threadfence_block();
            }
            if (lane == 0) assignedS = assigned;
        }
    }
    __syncthreads();

    for (int o = tid; o < 5120; o += 1024) {
        int b = o / 10, c = o - b * 10;
        unsigned d = Dls[b];
        float norm = fmaxf((float)__popc(d & 255), 1.0f);
        float sum = 0.f;
        #pragma unroll
        for (int e = 0; e < 8; ++e)
            if ((d >> e) & 1)
                sum += confG[b * 8 + e] * logitsG[(b * 8 + e) * 10 + c];
        outv[o] = sum / norm;
    }
    for (int t = tid; t < 4096; t += 1024) {
        outv[5120 + t] = confG[t];
        outv[9216 + t] = (float)((Dls[t >> 3] >> (t & 7)) & 1);
    }
}

// ============================ launch ============================
extern "C" void kernel_launch(void* const* d_in, const int* in_sizes, int n_in,
                              void* d_out, int out_size, void* d_ws, size_t ws_size,
                              hipStream_t stream)
{
    const float* x    = (const float*)d_in[0];
    const float* w0   = (const float*)d_in[1];
    const float* b0   = (const float*)d_in[2];
    const float* g0   = (const float*)d_in[3];
    const float* bt0  = (const float*)d_in[4];
    const float* rm0  = (const float*)d_in[5];
    const float* rv0  = (const float*)d_in[6];
    const float* w1   = (const float*)d_in[7];
    const float* b1   = (const float*)d_in[8];
    const float* g1   = (const float*)d_in[9];
    const float* bt1  = (const float*)d_in[10];
    const float* rm1  = (const float*)d_in[11];
    const float* rv1  = (const float*)d_in[12];
    const float* w2   = (const float*)d_in[13];
    const float* b2   = (const float*)d_in[14];
    const float* g2   = (const float*)d_in[15];
    const float* bt2  = (const float*)d_in[16];
    const float* rm2  = (const float*)d_in[17];
    const float* rv2  = (const float*)d_in[18];
    const float* w3   = (const float*)d_in[19];
    const float* b3   = (const float*)d_in[20];
    const float* g3   = (const float*)d_in[21];
    const float* bt3  = (const float*)d_in[22];
    const float* rm3  = (const float*)d_in[23];
    const float* rv3  = (const float*)d_in[24];
    const float* cls_w = (const float*)d_in[25];
    const float* cls_b = (const float*)d_in[26];
    float* outp = (float*)d_out;

    char* ws = (char*)d_ws;
    u16* A1H = (u16*)(ws);
    u16* A1L = (u16*)(ws + 21233664);
    u16* A0H = (u16*)(ws + 42467328);
    u16* A0L = (u16*)(ws + 42467328 + 37879808);
    u16* A2H = (u16*)(ws + 42467328);
    u16* A2L = (u16*)(ws + 42467328 + 42467328);
    u16* W1H = (u16*)(ws + 127401984);
    u16* W1L = (u16*)(ws + 127438848);
    u16* W2H = (u16*)(ws + 127475712);
    u16* W2L = (u16*)(ws + 127623168);
    u16* W3H = (u16*)(ws + 127770624);
    u16* W3L = (u16*)(ws + 128360448);
    float* BS1 = (float*)(ws + 128950272);
    float* BS2 = (float*)(ws + 128950528);
    float* BS3 = (float*)(ws + 128951040);
    float* featsPart = (float*)(ws + 128952064);   // [2][512][256]
    float* logits    = (float*)(ws + 130000640);
    float* conf      = (float*)(ws + 130164480);
    // presort output: 8KB, placed in the (dead-after-conv3) A2H region
    u16* sidx0 = (u16*)(ws + 42467328);

    ring_kernel<34, 34, 32><<<(512 * 132 * 4 + 255) / 256, 256, 0, stream>>>(A0H, A0L);
    ring_kernel<18, 18, 64><<<(512 * 68 * 8 + 255) / 256, 256, 0, stream>>>(A1H, A1L);
    wprep_kernel<32, 64><<<8, 256, 0, stream>>>(w1, b1, g1, bt1, rm1, rv1, W1H, W1L, BS1);
    wprep_kernel<64, 128><<<32, 256, 0, stream>>>(w2, b2, g2, bt2, rm2, rv2, W2H, W2L, BS2);
    wprep_kernel<128, 256><<<128, 256, 0, stream>>>(w3, b3, g3, bt3, rm3, rv3, W3H, W3L, BS3);

    conv0_kernel<<<2048, 256, 0, stream>>>(x, w0, b0, g0, bt0, rm0, rv0, A0H, A0L);
    convM_kernel<32, 64, 32, 32, 256, 64, 1>
        <<<dim3(2048, 1), 256, 0, stream>>>(A0H, A0L, W1H, W1L, BS1, A1H, A1L, nullptr);
    ring_kernel<18, 18, 128><<<(512 * 68 * 16 + 255) / 256, 256, 0, stream>>>(A2H, A2L);
    convM_kernel<64, 128, 16, 16, 128, 128, 0>
        <<<dim3(1024, 1), 256, 0, stream>>>(A1H, A1L, W2H, W2L, BS2, A2H, A2L, nullptr);
    convM_kernel<128, 256, 16, 16, 128, 128, 2>
        <<<dim3(1024, 2), 256, 0, stream>>>(A2H, A2L, W3H, W3L, BS3, nullptr, nullptr, featsPart);
    head_kernel<<<512, 128, 0, stream>>>(featsPart, cls_w, cls_b, logits, conf);
    presort_kernel<<<8, 256, 0, stream>>>(conf, sidx0);
    route_kernel<<<1, 1024, 0, stream>>>(conf, logits, sidx0, outp);
}

// Round 6
// 605.890 us; speedup vs baseline: 7.3469x; 1.0118x over previous
//
#include <hip/hip_runtime.h>
#include <hip/hip_bf16.h>
#include <cstdint>
#include <cstddef>

#define EPSV 1e-5f
typedef unsigned short u16;
using short8 = __attribute__((ext_vector_type(8))) short;
using f32x4  = __attribute__((ext_vector_type(4))) float;

typedef __attribute__((address_space(1))) void* gp1;
typedef __attribute__((address_space(3))) void* lp3;

__device__ __forceinline__ void gload16(const void* g, void* l) {
    __builtin_amdgcn_global_load_lds((gp1)(void*)g, (lp3)l, 16, 0, 0);
}
__device__ __forceinline__ u16 f2bf(float v) {
    __hip_bfloat16 h = __float2bfloat16(v);
    return *reinterpret_cast<u16*>(&h);
}
__device__ __forceinline__ float bf2f(u16 u) {
    __hip_bfloat16 h; *reinterpret_cast<u16*>(&h) = u;
    return __bfloat162float(h);
}

// ============ ring zero: zero the 1-px border of padded NHWC bf16 planes ============
template<int PH2, int PW2, int C>
__global__ __launch_bounds__(256) void ring_kernel(u16* __restrict__ bh, u16* __restrict__ bl)
{
    constexpr int RN = 2 * PW2 + 2 * (PH2 - 2);
    constexpr int C8 = C / 8;
    int id = blockIdx.x * 256 + (int)threadIdx.x;
    if (id >= 512 * RN * C8) return;
    int c8 = id % C8; int t = id / C8;
    int rp = t % RN;  int im = t / RN;
    int py, px;
    if (rp < PW2)            { py = 0;       px = rp; }
    else if (rp < 2 * PW2)   { py = PH2 - 1; px = rp - PW2; }
    else { int rr = rp - 2 * PW2; py = 1 + (rr >> 1); px = (rr & 1) ? (PW2 - 1) : 0; }
    size_t off = ((size_t)(im * PH2 + py) * PW2 + px) * C + c8 * 8;
    uint4 z = {0u, 0u, 0u, 0u};
    *(uint4*)(bh + off) = z;
    *(uint4*)(bl + off) = z;
}

// ============ weight prep: fold BN scale, transpose to [9][Cout][Cin], split bf16 ============
template<int CIN, int COUT>
__global__ __launch_bounds__(256) void wprep_kernel(
    const float* __restrict__ w, const float* __restrict__ b,
    const float* __restrict__ g, const float* __restrict__ bt,
    const float* __restrict__ rm, const float* __restrict__ rv,
    u16* __restrict__ WH, u16* __restrict__ WL, float* __restrict__ bias)
{
    int id = blockIdx.x * 256 + (int)threadIdx.x;
    if (id >= CIN * COUT) return;
    int co = id / CIN, ci = id % CIN;
    float s = g[co] / sqrtf(rv[co] + EPSV);
    #pragma unroll
    for (int k = 0; k < 9; ++k) {
        float v = w[((size_t)co * CIN + ci) * 9 + k] * s;
        u16 hh = f2bf(v);
        size_t o = ((size_t)k * COUT + co) * CIN + ci;
        WH[o] = hh;
        WL[o] = f2bf(v - bf2f(hh));
    }
    if (ci == 0) bias[co] = (b[co] - rm[co]) * s + bt[co];
}

// ============ conv0: 3->32, fp32 vector math, out = padded NHWC split-bf16 ============
__global__ __launch_bounds__(256) void conv0_kernel(
    const float* __restrict__ x, const float* __restrict__ w,
    const float* __restrict__ bias, const float* __restrict__ g,
    const float* __restrict__ bt, const float* __restrict__ rm,
    const float* __restrict__ rv, u16* __restrict__ Oh, u16* __restrict__ Ol)
{
    const int blk = blockIdx.x;            // 2048 blocks
    const int img = blk >> 2;
    const int p = ((blk & 3) << 8) | (int)threadIdx.x;   // pixel 0..1023
    const int y = p >> 5, xx = p & 31;
    const float* xin = x + (size_t)img * 3 * 1024;
    float xv[3][9];
    #pragma unroll
    for (int ci = 0; ci < 3; ++ci)
      #pragma unroll
      for (int ky = 0; ky < 3; ++ky)
        #pragma unroll
        for (int kx = 0; kx < 3; ++kx) {
            int yy = y + ky - 1, xc = xx + kx - 1;
            bool v = (yy >= 0) && (yy < 32) && (xc >= 0) && (xc < 32);
            xv[ci][ky * 3 + kx] = v ? xin[ci * 1024 + yy * 32 + xc] : 0.0f;
        }
    union { u16 u[32]; uint4 v4[4]; } oh, ol;
    #pragma unroll
    for (int co = 0; co < 32; ++co) {
        float s = g[co] / sqrtf(rv[co] + EPSV);
        float c = (bias[co] - rm[co]) * s + bt[co];
        float acc = 0.f;
        #pragma unroll
        for (int ci = 0; ci < 3; ++ci)
          #pragma unroll
          for (int k = 0; k < 9; ++k)
            acc += w[(co * 3 + ci) * 9 + k] * xv[ci][k];
        float v = acc * s + c;
        v = v > 0.f ? v : 0.f;
        u16 hh = f2bf(v);
        oh.u[co] = hh;
        ol.u[co] = f2bf(v - bf2f(hh));
    }
    size_t po = ((size_t)(img * 34 + y + 1) * 34 + xx + 1) * 32;
    #pragma unroll
    for (int q = 0; q < 4; ++q) {
        ((uint4*)(Oh + po))[q] = oh.v4[q];
        ((uint4*)(Ol + po))[q] = ol.v4[q];
    }
}

// ============ MFMA conv: shift-and-GEMM, split-bf16, padded NHWC in/out ============
// LDS layout swizzle: 16B chunk q of 64B line p lives at slot ((q + (p>>1)) & 3).
// 16 consecutive lines then touch each bank-group exactly 2x (2-way = free, m136)
// instead of the unswizzled 8-way conflict on stride-64B ds_read_b128.
template<int CIN, int COUT, int H, int W, int BM, int BN, int MODE>
__global__ __launch_bounds__(256, 2) void convM_kernel(
    const u16* __restrict__ Ah, const u16* __restrict__ Al,
    const u16* __restrict__ Wh, const u16* __restrict__ Wl,
    const float* __restrict__ bias,
    u16* __restrict__ Oh, u16* __restrict__ Ol, float* __restrict__ featsPart)
{
    constexpr int KC = CIN / 32;
    constexpr int ROWS = BM / W;
    constexpr int WM = BM / 64;
    constexpr int PW = W + 2;
    constexpr int AT = (ROWS + 2) * PW;
    constexpr int ACH = AT * 4;
    constexpr int BCH = BN * 4;
    constexpr int LW2 = (W == 32) ? 5 : 4;
    constexpr int MPI = (H * W) / BM;

    __shared__ u16 lA[2][AT * 32];
    __shared__ u16 lB[2][BN * 32];

    const int tid = (int)threadIdx.x;
    const int lane = tid & 63;
    const int wv = tid >> 6;
    const int wm = (WM == 4) ? wv : (wv >> 1);
    const int wn = (WM == 4) ? 0 : (wv & 1);
    const int l15 = lane & 15, quad = lane >> 4;

    const int mblk = (int)blockIdx.x, nblk = (int)blockIdx.y;
    const int img = mblk / MPI;
    const int y0 = (mblk % MPI) * ROWS;
    const size_t imgRow = (size_t)img * (H + 2);

    f32x4 acc[4][4];
    f32x4 zz = {0.f, 0.f, 0.f, 0.f};
    #pragma unroll
    for (int i = 0; i < 4; ++i)
      #pragma unroll
      for (int j = 0; j < 4; ++j) acc[i][j] = zz;

    for (int cb = 0; cb < KC; ++cb) {
        __syncthreads();
        // ---- stage A halo tile, swizzled: lane at LDS chunk id fetches global
        //      chunk s = ((id&3) - (p>>1)) & 3 of line p (same 64B line, permuted)
        #pragma unroll
        for (int it = 0; it < (ACH + 255) / 256; ++it) {
            int id = it * 256 + tid;
            if (id < ACH) {
                int p = id >> 2;
                int s = ((id & 3) - (p >> 1)) & 3;
                int yy = p / PW, xx = p - yy * PW;
                size_t ge = ((imgRow + y0 + yy) * PW + xx) * CIN + cb * 32 + s * 8;
                u16* ld = (u16*)&lA[0][0] + (size_t)(it * 256 + wv * 64) * 8;
                gload16(Ah + ge, ld);
                gload16(Al + ge, ld + AT * 32);
            }
        }
        for (int sh = 0; sh < 9; ++sh) {
            const int ky = sh / 3, kx = sh - 3 * (sh / 3);
            if (sh) __syncthreads();
            // ---- stage B chunk, same swizzle over rows n
            #pragma unroll
            for (int it = 0; it < (BCH + 255) / 256; ++it) {
                int id = it * 256 + tid;
                if (id < BCH) {
                    int n = id >> 2;
                    int s = ((id & 3) - (n >> 1)) & 3;
                    size_t ge = ((size_t)sh * COUT + nblk * BN + n) * CIN + cb * 32 + s * 8;
                    u16* ld = (u16*)&lB[0][0] + (size_t)(it * 256 + wv * 64) * 8;
                    gload16(Wh + ge, ld);
                    gload16(Wl + ge, ld + BN * 32);
                }
            }
            __syncthreads();
            short8 bh[4], bl[4];
            #pragma unroll
            for (int nt = 0; nt < 4; ++nt) {
                int nrow = wn * 64 + nt * 16 + l15;
                int boff = nrow * 32 + (((quad + (nrow >> 1)) & 3) * 8);
                bh[nt] = *(const short8*)&lB[0][boff];
                bl[nt] = *(const short8*)&lB[1][boff];
            }
            #pragma unroll
            for (int mt = 0; mt < 4; ++mt) {
                int p = wm * 64 + mt * 16 + l15;
                int yl = p >> LW2, xl = p & (W - 1);
                int pix = (yl + ky) * PW + xl + kx;
                int aoff = pix * 32 + (((quad + (pix >> 1)) & 3) * 8);
                short8 ah = *(const short8*)&lA[0][aoff];
                short8 al = *(const short8*)&lA[1][aoff];
                #pragma unroll
                for (int nt = 0; nt < 4; ++nt) {
                    acc[mt][nt] = __builtin_amdgcn_mfma_f32_16x16x32_bf16(ah, bh[nt], acc[mt][nt], 0, 0, 0);
                    acc[mt][nt] = __builtin_amdgcn_mfma_f32_16x16x32_bf16(ah, bl[nt], acc[mt][nt], 0, 0, 0);
                    acc[mt][nt] = __builtin_amdgcn_mfma_f32_16x16x32_bf16(al, bh[nt], acc[mt][nt], 0, 0, 0);
                }
            }
        }
    }

    if constexpr (MODE == 0) {
        #pragma unroll
        for (int mt = 0; mt < 4; ++mt) {
            int pbase = wm * 64 + mt * 16 + quad * 4;
            int yy = pbase >> LW2;
            #pragma unroll
            for (int nt = 0; nt < 4; ++nt) {
                int n = nblk * BN + wn * 64 + nt * 16 + l15;
                float bs = bias[n];
                #pragma unroll
                for (int r = 0; r < 4; ++r) {
                    int xx = (pbase & (W - 1)) + r;
                    float v = acc[mt][nt][r] + bs; v = v > 0.f ? v : 0.f;
                    size_t oo = ((size_t)(img * (H + 2) + y0 + yy + 1) * (W + 2) + xx + 1) * COUT + n;
                    u16 hh = f2bf(v);
                    Oh[oo] = hh;
                    Ol[oo] = f2bf(v - bf2f(hh));
                }
            }
        }
    } else if constexpr (MODE == 1) {
        #pragma unroll
        for (int nt = 0; nt < 4; ++nt) {
            int n = nt * 16 + l15;
            float bs = bias[n];
            #pragma unroll
            for (int mb = 0; mb < 2; ++mb) {
                #pragma unroll
                for (int xp = 0; xp < 2; ++xp) {
                    float v = fmaxf(fmaxf(acc[mb][nt][2 * xp], acc[mb][nt][2 * xp + 1]),
                                    fmaxf(acc[mb + 2][nt][2 * xp], acc[mb + 2][nt][2 * xp + 1]));
                    v += bs; v = v > 0.f ? v : 0.f;
                    int py = (y0 >> 1) + wm;
                    int px = mb * 8 + quad * 2 + xp;
                    size_t oo = ((size_t)(img * 18 + py + 1) * 18 + px + 1) * COUT + n;
                    u16 hh = f2bf(v);
                    Oh[oo] = hh;
                    Ol[oo] = f2bf(v - bf2f(hh));
                }
            }
        }
    } else {
        __shared__ float fbuf[2][128];
        #pragma unroll
        for (int nt = 0; nt < 4; ++nt) {
            float bs = bias[nblk * BN + wn * 64 + nt * 16 + l15];
            float s = 0.f;
            #pragma unroll
            for (int mp = 0; mp < 2; ++mp)
              #pragma unroll
              for (int xp = 0; xp < 2; ++xp) {
                  float v = fmaxf(fmaxf(acc[2 * mp][nt][2 * xp], acc[2 * mp][nt][2 * xp + 1]),
                                  fmaxf(acc[2 * mp + 1][nt][2 * xp], acc[2 * mp + 1][nt][2 * xp + 1]));
                  v += bs; v = v > 0.f ? v : 0.f;
                  s += v;
              }
            s += __shfl_xor(s, 16, 64);
            s += __shfl_xor(s, 32, 64);
            if (quad == 0) fbuf[wm][wn * 64 + nt * 16 + l15] = s;
        }
        __syncthreads();
        if (tid < 128) {
            float f = (fbuf[0][tid] + fbuf[1][tid]) * (1.0f / 64.0f);
            featsPart[((size_t)(mblk % MPI) * 512 + img) * 256 + nblk * BN + tid] = f;
        }
    }
}

// ============== head GEMM + log-softmax + conf ==============
__global__ __launch_bounds__(128) void head_kernel(
    const float* __restrict__ featsPart, const float* __restrict__ cls_w,
    const float* __restrict__ cls_b, float* __restrict__ logits,
    float* __restrict__ conf)
{
    __shared__ float f[256];
    __shared__ float wt[80 * 65];
    __shared__ float lg[80];
    const int b = blockIdx.x, tid = (int)threadIdx.x;
    f[tid]       = featsPart[b * 256 + tid]       + featsPart[131072 + b * 256 + tid];
    f[tid + 128] = featsPart[b * 256 + tid + 128] + featsPart[131072 + b * 256 + tid + 128];
    float acc = 0.f;
    for (int ch = 0; ch < 4; ++ch) {
        __syncthreads();
        for (int q = tid; q < 80 * 64; q += 128) {
            int r = q >> 6, cc = q & 63;
            wt[r * 65 + cc] = cls_w[r * 256 + ch * 64 + cc];
        }
        __syncthreads();
        if (tid < 80) {
            #pragma unroll 8
            for (int dd = 0; dd < 64; ++dd)
                acc += wt[tid * 65 + dd] * f[ch * 64 + dd];
        }
    }
    if (tid < 80) {
        acc += cls_b[tid];
        logits[b * 80 + tid] = acc;
        lg[tid] = acc;
    }
    __syncthreads();
    if (tid < 80 && (tid % 10) == 0) {
        const int e = tid / 10;
        float m = lg[e * 10];
        for (int cc = 1; cc < 10; ++cc) m = fmaxf(m, lg[e * 10 + cc]);
        float ssum = 0.f;
        for (int cc = 0; cc < 10; ++cc) ssum += expf(lg[e * 10 + cc] - m);
        float lz = m + logf(ssum);
        float cf = 0.f;
        for (int cc = 0; cc < 10; ++cc) {
            float lp = lg[e * 10 + cc] - lz;
            cf += expf(lp) * lp;
        }
        conf[b * 8 + e] = cf;
    }
}

// ======= presort: per-expert descending sort of conf (done ONCE) =======
__global__ __launch_bounds__(256) void presort_kernel(
    const float* __restrict__ confG, u16* __restrict__ sidx0)
{
    __shared__ float v[512];
    __shared__ u16 bi[512];
    const int j = (int)blockIdx.x, tid = (int)threadIdx.x;
    for (int r = tid; r < 512; r += 256) { v[r] = confG[r * 8 + j]; bi[r] = (u16)r; }
    for (int k = 2; k <= 512; k <<= 1)
        for (int jj = k >> 1; jj > 0; jj >>= 1) {
            __syncthreads();
            int i = ((tid & ~(jj - 1)) << 1) | (tid & (jj - 1));
            int p = i | jj;
            float va = v[i], vb = v[p];
            u16 ia = bi[i], ib = bi[p];
            bool first = (va > vb) || (va == vb && ia < ib);
            bool up = (i & k) == 0;
            if (up ? !first : first) { v[i] = vb; v[p] = va; bi[i] = ib; bi[p] = ia; }
        }
    __syncthreads();
    for (int r = tid; r < 512; r += 256)
        sidx0[j * 512 + r] = (u16)(bi[r] * 8 + j);
}

// ======= routing: per cycle [rescale -> 3-level merge-path -> greedy scan] + final =======
__global__ __launch_bounds__(1024) void route_kernel(
    const float* __restrict__ confG,   // [512*8]
    const float* __restrict__ logitsG, // [512*80]
    const u16*   __restrict__ sidx0,   // [4096] presorted per-expert idx lists
    float* __restrict__ outv)          // [5120 final | 4096 conf | 4096 D]
{
    __shared__ float valById[4096];
    __shared__ float sv[4096];
    __shared__ u16 P[4096];
    __shared__ u16 mA[4096];
    __shared__ u16 mB[4096];
    __shared__ unsigned char Dls[512];
    __shared__ int ec[8];
    __shared__ int assignedS;
    const int tid = (int)threadIdx.x;

    for (int t = tid; t < 4096; t += 1024) {
        valById[t] = confG[t];
        P[t] = sidx0[t];
    }
    if (tid < 512) Dls[tid] = 0;
    if (tid < 8) ec[tid] = 0;
    if (tid == 0) assignedS = 0;

    auto earlier = [&](u16 a, u16 b) -> bool {
        float va = sv[a], vb = sv[b];
        return (va > vb) || (va == vb && a < b);
    };
    auto mergeChunk = [&](const u16* X, const u16* Y, int n, int o0, u16* out) {
        int lo = o0 - n; if (lo < 0) lo = 0;
        int hi = o0 < n ? o0 : n;
        while (lo < hi) {
            int mid = (lo + hi) >> 1;
            if (earlier(X[mid], Y[o0 - 1 - mid])) lo = mid + 1; else hi = mid;
        }
        int i = lo, jj = o0 - lo;
        #pragma unroll
        for (int q = 0; q < 4; ++q) {
            u16 xc = X[i < n ? i : (n - 1)];
            u16 yc = Y[jj < n ? jj : (n - 1)];
            bool takeX = (jj >= n) || ((i < n) && earlier(xc, yc));
            out[q] = takeX ? xc : yc;
            if (takeX) ++i; else ++jj;
        }
    };

    for (int cycle = 0; cycle < 4; ++cycle) {
        __syncthreads();
        for (int t = tid; t < 4096; t += 1024) {
            float sc = 1.0f - ((float)ec[t & 7]) / 160.0f;
            sv[t] = valById[t] * sc;
        }
        __syncthreads();
        {   // L1: P (8 lists of 512) -> mA (4 lists of 1024)
            int g = tid << 2;
            int p = g >> 10, o0 = g & 1023;
            mergeChunk(&P[(p << 1) * 512], &P[(p << 1) * 512 + 512], 512, o0, &mA[(p << 10) + o0]);
        }
        __syncthreads();
        {   // L2: mA -> mB (2 lists of 2048)
            int g = tid << 2;
            int p = g >> 11, o0 = g & 2047;
            mergeChunk(&mA[p << 11], &mA[(p << 11) + 1024], 1024, o0, &mB[(p << 11) + o0]);
        }
        __syncthreads();
        {   // L3: mB -> mA (full 4096 order, descending)
            int o0 = tid << 2;
            mergeChunk(&mB[0], &mB[2048], 2048, o0, &mA[o0]);
        }
        __syncthreads();
        if (tid < 64) {
            const int lane = tid;
            int cyc = 0;
            int assigned = assignedS;
            for (int chunk = 0; chunk < 64; ++chunk) {
                if (cyc >= 256 || assigned >= 1024) break;
                int id = mA[(chunk << 6) | lane];
                int b = id >> 3, j = id & 7;
                unsigned d = Dls[b];
                bool notA = ((d >> j) & 1) == 0;
                int ecj = ec[j];
                int scb = __popc(d & 255);
                unsigned long long sb = ~0ull;
                #pragma unroll
                for (int t2 = 0; t2 < 9; ++t2) {
                    unsigned long long bl = __ballot((b >> t2) & 1);
                    sb &= ((b >> t2) & 1) ? bl : ~bl;
                }
                unsigned long long jb0 = __ballot(j & 1);
                unsigned long long jb1 = __ballot((j >> 1) & 1);
                unsigned long long jb2 = __ballot((j >> 2) & 1);
                unsigned long long sj = ((j & 1) ? jb0 : ~jb0) &
                                        ((j & 2) ? jb1 : ~jb1) &
                                        ((j & 4) ? jb2 : ~jb2);
                unsigned long long earlierM = (1ull << lane) - 1ull;
                bool ok = notA && (ecj < 160) && (scb < 2);
                unsigned long long okm = __ballot(ok);
                for (int it = 0; it < 64; ++it) {
                    unsigned long long em = okm & earlierM;
                    int aE = __popcll(em & sj);
                    int aS = __popcll(em & sb);
                    int aC = __popcll(em);
                    bool ok2 = notA && (ecj + aE) < 160 && (scb + aS) < 2 &&
                               (cyc + aC) < 256 && (assigned + aC) < 1024;
                    unsigned long long okm2 = __ballot(ok2);
                    ok = ok2;
                    if (okm2 == okm) break;
                    okm = okm2;
                }
                int add = __popcll(okm);
                if (lane < 8) {
                    unsigned long long mj = ((lane & 1) ? jb0 : ~jb0) &
                                            ((lane & 2) ? jb1 : ~jb1) &
                                            ((lane & 4) ? jb2 : ~jb2);
                    int c2 = __popcll(mj & okm);
                    if (c2) ec[lane] += c2;
                }
                if (ok) {
                    unsigned long long grp = okm & sb;
                    if (lane == __builtin_ctzll(grp)) {
                        unsigned orb = 0;
                        #pragma unroll
                        for (int jj2 = 0; jj2 < 8; ++jj2) {
                            unsigned long long mj2 = ((jj2 & 1) ? jb0 : ~jb0) &
                                                     ((jj2 & 2) ? jb1 : ~jb1) &
                                                     ((jj2 & 4) ? jb2 : ~jb2);
                            if (mj2 & grp) orb |= (1u << jj2);
                        }
                        Dls[b] = (unsigned char)(d | orb);
                    }
                }
                cyc += add;
                assigned += add;
                __threadfence_block();
            }
            if (lane == 0) assignedS = assigned;
        }
    }
    __syncthreads();

    for (int o = tid; o < 5120; o += 1024) {
        int b = o / 10, c = o - b * 10;
        unsigned d = Dls[b];
        float norm = fmaxf((float)__popc(d & 255), 1.0f);
        float sum = 0.f;
        #pragma unroll
        for (int e = 0; e < 8; ++e)
            if ((d >> e) & 1)
                sum += confG[b * 8 + e] * logitsG[(b * 8 + e) * 10 + c];
        outv[o] = sum / norm;
    }
    for (int t = tid; t < 4096; t += 1024) {
        outv[5120 + t] = confG[t];
        outv[9216 + t] = (float)((Dls[t >> 3] >> (t & 7)) & 1);
    }
}

// ============================ launch ============================
extern "C" void kernel_launch(void* const* d_in, const int* in_sizes, int n_in,
                              void* d_out, int out_size, void* d_ws, size_t ws_size,
                              hipStream_t stream)
{
    const float* x    = (const float*)d_in[0];
    const float* w0   = (const float*)d_in[1];
    const float* b0   = (const float*)d_in[2];
    const float* g0   = (const float*)d_in[3];
    const float* bt0  = (const float*)d_in[4];
    const float* rm0  = (const float*)d_in[5];
    const float* rv0  = (const float*)d_in[6];
    const float* w1   = (const float*)d_in[7];
    const float* b1   = (const float*)d_in[8];
    const float* g1   = (const float*)d_in[9];
    const float* bt1  = (const float*)d_in[10];
    const float* rm1  = (const float*)d_in[11];
    const float* rv1  = (const float*)d_in[12];
    const float* w2   = (const float*)d_in[13];
    const float* b2   = (const float*)d_in[14];
    const float* g2   = (const float*)d_in[15];
    const float* bt2  = (const float*)d_in[16];
    const float* rm2  = (const float*)d_in[17];
    const float* rv2  = (const float*)d_in[18];
    const float* w3   = (const float*)d_in[19];
    const float* b3   = (const float*)d_in[20];
    const float* g3   = (const float*)d_in[21];
    const float* bt3  = (const float*)d_in[22];
    const float* rm3  = (const float*)d_in[23];
    const float* rv3  = (const float*)d_in[24];
    const float* cls_w = (const float*)d_in[25];
    const float* cls_b = (const float*)d_in[26];
    float* outp = (float*)d_out;

    char* ws = (char*)d_ws;
    u16* A1H = (u16*)(ws);
    u16* A1L = (u16*)(ws + 21233664);
    u16* A0H = (u16*)(ws + 42467328);
    u16* A0L = (u16*)(ws + 42467328 + 37879808);
    u16* A2H = (u16*)(ws + 42467328);
    u16* A2L = (u16*)(ws + 42467328 + 42467328);
    u16* W1H = (u16*)(ws + 127401984);
    u16* W1L = (u16*)(ws + 127438848);
    u16* W2H = (u16*)(ws + 127475712);
    u16* W2L = (u16*)(ws + 127623168);
    u16* W3H = (u16*)(ws + 127770624);
    u16* W3L = (u16*)(ws + 128360448);
    float* BS1 = (float*)(ws + 128950272);
    float* BS2 = (float*)(ws + 128950528);
    float* BS3 = (float*)(ws + 128951040);
    float* featsPart = (float*)(ws + 128952064);   // [2][512][256]
    float* logits    = (float*)(ws + 130000640);
    float* conf      = (float*)(ws + 130164480);
    u16* sidx0 = (u16*)(ws + 42467328);            // dead-after-conv3 region

    ring_kernel<34, 34, 32><<<(512 * 132 * 4 + 255) / 256, 256, 0, stream>>>(A0H, A0L);
    ring_kernel<18, 18, 64><<<(512 * 68 * 8 + 255) / 256, 256, 0, stream>>>(A1H, A1L);
    wprep_kernel<32, 64><<<8, 256, 0, stream>>>(w1, b1, g1, bt1, rm1, rv1, W1H, W1L, BS1);
    wprep_kernel<64, 128><<<32, 256, 0, stream>>>(w2, b2, g2, bt2, rm2, rv2, W2H, W2L, BS2);
    wprep_kernel<128, 256><<<128, 256, 0, stream>>>(w3, b3, g3, bt3, rm3, rv3, W3H, W3L, BS3);

    conv0_kernel<<<2048, 256, 0, stream>>>(x, w0, b0, g0, bt0, rm0, rv0, A0H, A0L);
    convM_kernel<32, 64, 32, 32, 256, 64, 1>
        <<<dim3(2048, 1), 256, 0, stream>>>(A0H, A0L, W1H, W1L, BS1, A1H, A1L, nullptr);
    ring_kernel<18, 18, 128><<<(512 * 68 * 16 + 255) / 256, 256, 0, stream>>>(A2H, A2L);
    convM_kernel<64, 128, 16, 16, 128, 128, 0>
        <<<dim3(1024, 1), 256, 0, stream>>>(A1H, A1L, W2H, W2L, BS2, A2H, A2L, nullptr);
    convM_kernel<128, 256, 16, 16, 128, 128, 2>
        <<<dim3(1024, 2), 256, 0, stream>>>(A2H, A2L, W3H, W3L, BS3, nullptr, nullptr, featsPart);
    head_kernel<<<512, 128, 0, stream>>>(featsPart, cls_w, cls_b, logits, conf);
    presort_kernel<<<8, 256, 0, stream>>>(conf, sidx0);
    route_kernel<<<1, 1024, 0, stream>>>(conf, logits, sidx0, outp);
}